// Round 2
// baseline (9520.691 us; speedup 1.0000x reference)
//
#include <hip/hip_runtime.h>

#define SS 4096
#define LL 16
#define HD 512
#define ECD 128
#define HHD 256

typedef __attribute__((ext_vector_type(8))) short short8;
typedef __attribute__((ext_vector_type(4))) float float4v;
typedef _Float16 half2v __attribute__((ext_vector_type(2)));

__device__ __forceinline__ float bf2f(unsigned short u){
  union { unsigned int i; float f; } v; v.i = ((unsigned int)u) << 16; return v.f;
}
__device__ __forceinline__ unsigned short f2bf(float f){
  union { float f; unsigned int i; } v; v.f = f;
  unsigned int u = v.i;
  unsigned int r = (u + 0x7fffu + ((u >> 16) & 1u)) >> 16;
  return (unsigned short)r;
}
__device__ __forceinline__ unsigned short f2h(float x){
  _Float16 h = (_Float16)x;
  return __builtin_bit_cast(unsigned short, h);
}
__device__ __forceinline__ float sigf(float x){ return 1.f / (1.f + __expf(-x)); }
__device__ __forceinline__ float tanh_f(float x){
  float e = __expf(2.f * x);
  return 1.f - 2.f / (e + 1.f);
}
__device__ __forceinline__ float fdot2u(unsigned int a, unsigned int b, float c){
  half2v ha = __builtin_bit_cast(half2v, a);
  half2v hb = __builtin_bit_cast(half2v, b);
#if __has_builtin(__builtin_amdgcn_fdot2)
  return __builtin_amdgcn_fdot2(ha, hb, c, false);
#else
  return c + (float)ha[0]*(float)hb[0] + (float)ha[1]*(float)hb[1];
#endif
}
__device__ __forceinline__ unsigned int packf16(float lo, float hi){
  half2v h; h[0] = (_Float16)lo; h[1] = (_Float16)hi;
  return __builtin_bit_cast(unsigned int, h);
}
__device__ __forceinline__ bool badf(float x){ return !(fabsf(x) < 1e30f); }

// pack 8 f32 -> 8 bf16 (as int4) for LDS staging
__device__ __forceinline__ int4 cvt8(const float* __restrict__ s){
  union { unsigned short u[8]; int4 v; } pk;
#pragma unroll
  for (int i = 0; i < 8; ++i) pk.u[i] = f2bf(s[i]);
  return pk.v;
}

// ---------------- prep: xUb[c][n] = char_emb[c].Wih_c[n] + bih_c[n] + bhh_c[n]  (bf16 out)
__global__ void prep_xu_k(const float* __restrict__ char_emb,
                          const float* __restrict__ Wih_c,
                          const float* __restrict__ bih_c,
                          const float* __restrict__ bhh_c,
                          unsigned short* __restrict__ xUb)
{
  int idx = blockIdx.x * 256 + threadIdx.x;   // 512 * 2048
  int c = idx >> 11, n = idx & 2047;
  const float* ce = char_emb + (size_t)c * ECD;
  const float* wr = Wih_c + (size_t)n * ECD;
  float acc = bih_c[n] + bhh_c[n];
  for (int k = 0; k < ECD; k += 4) {
    float4 a = *(const float4*)(ce + k);
    float4 b = *(const float4*)(wr + k);
    acc += a.x*b.x + a.y*b.y + a.z*b.z + a.w*b.w;
  }
  xUb[idx] = f2bf(acc);
}

// ---------------- prep: h0 = prefix_emb[feat_seq] (bf16), c0 = 0 (bf16)
__global__ void prep_h0c0_k(const float* __restrict__ prefix_emb,
                            const int* __restrict__ feat_seq,
                            unsigned short* __restrict__ h0,
                            unsigned short* __restrict__ c0)
{
  int idx = blockIdx.x * 256 + threadIdx.x;  // 4096*512
  int s = idx >> 9, j = idx & 511;
  h0[idx] = f2bf(prefix_emb[(size_t)feat_seq[s] * HD + j]);
  c0[idx] = 0;
}

// ---------------- prep v2: pack Whh_{f,b} (f32) into [dir][q4 0..31][row 0..1023][j 0..3] u32 f16x2
// u32 index = (dir<<17) | (q4<<12) | (row<<2) | j ; covers k = 2*(q4*4+j), +1
__global__ void prep_scanw2_k(const float* __restrict__ Whh_f,
                              const float* __restrict__ Whh_b,
                              const float* __restrict__ bih_f,
                              const float* __restrict__ bhh_f,
                              const float* __restrict__ bih_b,
                              const float* __restrict__ bhh_b,
                              unsigned int* __restrict__ Wpk,
                              float* __restrict__ biasbuf,
                              int* __restrict__ diag)
{
  int idx = blockIdx.x * 256 + threadIdx.x;  // 2*32*1024*4 = 262144
  int j   = idx & 3;
  int row = (idx >> 2) & 1023;
  int q4  = (idx >> 12) & 31;
  int dir = (idx >> 17) & 1;
  int k = 2 * (q4 * 4 + j);
  const float* W = dir ? Whh_b : Whh_f;   // [1024,256] f32, rows gate-major i,f,g,o
  Wpk[idx] = packf16(W[(size_t)row * HHD + k], W[(size_t)row * HHD + k + 1]);
  if (idx < 2048) {
    int dr = idx >> 10, g = idx & 1023;
    biasbuf[idx] = dr ? (bih_b[g] + bhh_b[g]) : (bih_f[g] + bhh_f[g]);
  }
  if (idx == 0) diag[0] = 0;
}

// ---------------- fused char-step: gates = h_in @ Whh_c^T (MFMA), then LSTM cell epilogue
__global__ __launch_bounds__(256) void gemm_char_k(
    const unsigned short* __restrict__ hin,   // [4096,512] bf16
    const float* __restrict__ Whh,            // [2048,512] f32
    const unsigned short* __restrict__ xUb,   // [512,2048] bf16
    const int* __restrict__ chars,
    const int* __restrict__ lens,
    int t,
    unsigned short* __restrict__ hout,        // [4096,512] bf16
    unsigned short* __restrict__ cb,          // [4096,512] bf16 (in/out)
    int* __restrict__ diag)
{
  __shared__ __align__(16) unsigned short As[128 * 32];
  __shared__ __align__(16) unsigned short Bs[128 * 32];
  __shared__ __align__(16) unsigned short gates[128 * 136];
  const int tid = threadIdx.x;
  const int m0 = blockIdx.y * 128;
  const int n0h = blockIdx.x * 32;            // base h-column of this tile
  const int wave = tid >> 6;
  const int lane = tid & 63;
  const int wm = (wave >> 1) * 64;
  const int wn = (wave & 1) * 64;
  float4v z = {0.f, 0.f, 0.f, 0.f};
  float4v acc[4][4];
#pragma unroll
  for (int i = 0; i < 4; ++i)
#pragma unroll
    for (int j = 0; j < 4; ++j) acc[i][j] = z;

  for (int k0 = 0; k0 < 512; k0 += 32) {
    __syncthreads();
#pragma unroll
    for (int i = 0; i < 2; ++i) {
      int chunk = tid * 2 + i;           // 0..511
      int row = chunk >> 2;              // 0..127
      int k8 = (chunk & 3) * 8;
      int4 av = *(const int4*)(hin + (size_t)(m0 + row) * 512 + k0 + k8);
      *(int4*)(As + row * 32 + k8) = av;
      int br = (row >> 5) * 512 + n0h + (row & 31);
      *(int4*)(Bs + row * 32 + k8) = cvt8(Whh + (size_t)br * 512 + k0 + k8);
    }
    __syncthreads();
    short8 af[4], bfr[4];
    const int kq = (lane >> 4) * 8;
#pragma unroll
    for (int i = 0; i < 4; ++i) {
      af[i]  = *(const short8*)(As + (wm + i * 16 + (lane & 15)) * 32 + kq);
      bfr[i] = *(const short8*)(Bs + (wn + i * 16 + (lane & 15)) * 32 + kq);
    }
#pragma unroll
    for (int i = 0; i < 4; ++i)
#pragma unroll
      for (int j = 0; j < 4; ++j)
        acc[i][j] = __builtin_amdgcn_mfma_f32_16x16x32_bf16(af[i], bfr[j], acc[i][j], 0, 0, 0);
  }
  __syncthreads();
#pragma unroll
  for (int i = 0; i < 4; ++i)
#pragma unroll
    for (int j = 0; j < 4; ++j)
#pragma unroll
      for (int r = 0; r < 4; ++r) {
        int row = wm + i * 16 + (lane >> 4) * 4 + r;
        int col = wn + j * 16 + (lane & 15);
        gates[row * 136 + col] = f2bf(acc[i][j][r]);
      }
  __syncthreads();
#pragma unroll
  for (int e = 0; e < 16; ++e) {
    int idx = e * 256 + tid;
    int r = idx >> 5, hc = idx & 31;
    int s = m0 + r;
    int col = n0h + hc;
    if (t < lens[s]) {
      int cid = chars[s * LL + t];
      size_t xb = (size_t)cid * 2048 + col;
      float gi = bf2f(gates[r * 136 + hc])      + bf2f(xUb[xb]);
      float gf = bf2f(gates[r * 136 + 32 + hc]) + bf2f(xUb[xb + 512]);
      float gg = bf2f(gates[r * 136 + 64 + hc]) + bf2f(xUb[xb + 1024]);
      float go = bf2f(gates[r * 136 + 96 + hc]) + bf2f(xUb[xb + 1536]);
      if (badf(gi + gf + gg + go)) atomicOr(diag, 1);
      float cc = sigf(gf) * bf2f(cb[(size_t)s * 512 + col]) + sigf(gi) * tanh_f(gg);
      cb[(size_t)s * 512 + col] = f2bf(cc);
      hout[(size_t)s * 512 + col] = f2bf(sigf(go) * tanh_f(cc));
    } else {
      hout[(size_t)s * 512 + col] = hin[(size_t)s * 512 + col];
    }
  }
}

// ---------------- P GEMM: P[M=4096, N=1024](bf16) = [word_emb[wseq] f32 | h bf16] @ Wih^T(f32)
__global__ __launch_bounds__(256) void gemm_gather_nt_k(
    const float* __restrict__ wemb,
    const int* __restrict__ wseq,
    const unsigned short* __restrict__ hbuf,
    const float* __restrict__ B,              // [1024,1024] f32
    unsigned short* __restrict__ P)           // [4096,1024] bf16
{
  __shared__ __align__(16) unsigned short As[128 * 32];
  __shared__ __align__(16) unsigned short Bs[128 * 32];
  const int tid = threadIdx.x;
  const int m0 = blockIdx.y * 128;
  const int n0 = blockIdx.x * 128;
  const int wave = tid >> 6;
  const int lane = tid & 63;
  const int wm = (wave >> 1) * 64;
  const int wn = (wave & 1) * 64;
  float4v z = {0.f, 0.f, 0.f, 0.f};
  float4v acc[4][4];
#pragma unroll
  for (int i = 0; i < 4; ++i)
#pragma unroll
    for (int j = 0; j < 4; ++j) acc[i][j] = z;

  for (int k0 = 0; k0 < 1024; k0 += 32) {
    __syncthreads();
#pragma unroll
    for (int i = 0; i < 2; ++i) {
      int chunk = tid * 2 + i;
      int row = chunk >> 2;
      int k8 = (chunk & 3) * 8;
      int arow = m0 + row;
      int acol = k0 + k8;
      if (acol < 512) {
        *(int4*)(As + row * 32 + k8) = cvt8(wemb + (size_t)wseq[arow] * 512 + acol);
      } else {
        int4 av = *(const int4*)(hbuf + (size_t)arow * 512 + (acol - 512));
        *(int4*)(As + row * 32 + k8) = av;
      }
      *(int4*)(Bs + row * 32 + k8) = cvt8(B + (size_t)(n0 + row) * 1024 + k0 + k8);
    }
    __syncthreads();
    short8 af[4], bfr[4];
    const int kq = (lane >> 4) * 8;
#pragma unroll
    for (int i = 0; i < 4; ++i) {
      af[i]  = *(const short8*)(As + (wm + i * 16 + (lane & 15)) * 32 + kq);
      bfr[i] = *(const short8*)(Bs + (wn + i * 16 + (lane & 15)) * 32 + kq);
    }
#pragma unroll
    for (int i = 0; i < 4; ++i)
#pragma unroll
      for (int j = 0; j < 4; ++j)
        acc[i][j] = __builtin_amdgcn_mfma_f32_16x16x32_bf16(af[i], bfr[j], acc[i][j], 0, 0, 0);
  }
#pragma unroll
  for (int i = 0; i < 4; ++i)
#pragma unroll
    for (int j = 0; j < 4; ++j)
#pragma unroll
      for (int r = 0; r < 4; ++r) {
        int row = m0 + wm + i * 16 + (lane >> 4) * 4 + r;
        int col = n0 + wn + j * 16 + (lane & 15);
        P[(size_t)row * 1024 + col] = f2bf(acc[i][j][r]);
      }
}

// ---------------- scan v2: ONE block per direction, zero cross-block exchange.
// 512 threads; thread t owns gate rows rA=t (gates i/f) and rB=t+512 (gates g/o),
// full K=256 each. Weights: 28 q4-chunks (224 u32) in VGPRs + 4 q4-chunks in LDS (64 KB).
// h state (256 f16) + c state + gate buffer live in LDS; 2 barriers/step.
__global__ __launch_bounds__(512, 2) void scan2_k(
    const unsigned short* __restrict__ P_f,   // [4096,1024] bf16
    const unsigned short* __restrict__ P_b,
    const unsigned int* __restrict__ Wpk,     // [2][32][1024][4] u32 (f16x2)
    const float* __restrict__ biasbuf,        // [2][1024] f32
    unsigned short* __restrict__ out_f,       // [4096,256] bf16
    unsigned short* __restrict__ out_b,
    int* __restrict__ diag, int dirsel)
{
  const int dir = (dirsel < 0) ? (int)blockIdx.x : dirsel;
  const int tid = threadIdx.x;
  const int rA = tid;          // rows 0..511   (gate i: 0..255, gate f: 256..511)
  const int rB = tid + 512;    // rows 512..1023 (gate g, gate o)

  __shared__ __align__(16) uint4 ldsW[4 * 1024];          // 64 KB: chunks q4=28..31, [q4-28][row]
  __shared__ __align__(16) float g_lds[1024];
  __shared__ __align__(16) float c_lds[256];
  __shared__ __align__(16) unsigned short h16[256];       // f16 h state (32 uint4)

  const uint4* wp = (const uint4*)Wpk + (size_t)dir * 32 * 1024;
  uint4 wA[28], wB[28];
#pragma unroll
  for (int q4 = 0; q4 < 28; ++q4) {
    wA[q4] = wp[q4 * 1024 + rA];
    wB[q4] = wp[q4 * 1024 + rB];
  }
#pragma unroll
  for (int q4 = 28; q4 < 32; ++q4) {
    ldsW[(q4 - 28) * 1024 + rA] = wp[q4 * 1024 + rA];
    ldsW[(q4 - 28) * 1024 + rB] = wp[q4 * 1024 + rB];
  }
  const float bA = biasbuf[dir * 1024 + rA];
  const float bB = biasbuf[dir * 1024 + rB];
  const unsigned short* P = dir ? P_b : P_f;
  unsigned short* out = dir ? out_b : out_f;

  if (tid < 256) { h16[tid] = 0; c_lds[tid] = 0.f; }
  __syncthreads();

  for (int t = 0; t < 4096; ++t) {
    const int srow = dir ? (4095 - t) : t;
    // issue the two P loads first; consumed only at g_lds write (latency hidden)
    float pA = bf2f(P[(size_t)srow * 1024 + rA]);
    float pB = bf2f(P[(size_t)srow * 1024 + rB]);
    float accA = 0.f, accB = 0.f;
    const uint4* h4 = (const uint4*)h16;   // 32 broadcast chunks of 8 f16
#pragma unroll
    for (int q4 = 0; q4 < 28; ++q4) {
      uint4 hv = h4[q4];
      accA = fdot2u(wA[q4].x, hv.x, accA);
      accA = fdot2u(wA[q4].y, hv.y, accA);
      accA = fdot2u(wA[q4].z, hv.z, accA);
      accA = fdot2u(wA[q4].w, hv.w, accA);
      accB = fdot2u(wB[q4].x, hv.x, accB);
      accB = fdot2u(wB[q4].y, hv.y, accB);
      accB = fdot2u(wB[q4].z, hv.z, accB);
      accB = fdot2u(wB[q4].w, hv.w, accB);
    }
#pragma unroll
    for (int q4 = 28; q4 < 32; ++q4) {
      uint4 hv = h4[q4];
      uint4 wa = ldsW[(q4 - 28) * 1024 + rA];
      uint4 wb = ldsW[(q4 - 28) * 1024 + rB];
      accA = fdot2u(wa.x, hv.x, accA);
      accA = fdot2u(wa.y, hv.y, accA);
      accA = fdot2u(wa.z, hv.z, accA);
      accA = fdot2u(wa.w, hv.w, accA);
      accB = fdot2u(wb.x, hv.x, accB);
      accB = fdot2u(wb.y, hv.y, accB);
      accB = fdot2u(wb.z, hv.z, accB);
      accB = fdot2u(wb.w, hv.w, accB);
    }
    g_lds[rA] = accA + bA + pA;
    g_lds[rB] = accB + bB + pB;
    __syncthreads();            // gates ready; h16 fully consumed
    if (tid < 256) {
      float gi = g_lds[tid];
      float gf = g_lds[256 + tid];
      float gg = g_lds[512 + tid];
      float go = g_lds[768 + tid];
      if (badf(gi + gf + gg + go)) atomicOr(diag, 2);
      float cc = sigf(gf) * c_lds[tid] + sigf(gi) * tanh_f(gg);
      float hh = sigf(go) * tanh_f(cc);
      c_lds[tid] = cc;
      h16[tid] = f2h(hh);
      out[(size_t)srow * HHD + tid] = f2bf(hh);
    }
    __syncthreads();            // new h16 ready
  }
}

// ---------------- heads: logits + log_softmax -> f32 out
__global__ __launch_bounds__(128) void head_k(
    const unsigned short* __restrict__ out_f, const unsigned short* __restrict__ out_b,
    const float* __restrict__ Wpos, const float* __restrict__ bpos,
    const float* __restrict__ Wner, const float* __restrict__ bner,
    float* __restrict__ dout, int* __restrict__ diag)
{
  const int s = blockIdx.x, tid = threadIdx.x;
  __shared__ __align__(16) float xv[512];
#pragma unroll
  for (int i = 0; i < 4; ++i) {
    int k = tid * 4 + i;
    xv[k] = (k < 256) ? bf2f(out_f[(size_t)s * 256 + k])
                      : bf2f(out_b[(size_t)s * 256 + (k - 256)]);
  }
  __syncthreads();
  float logit = 0.f;
  const int j = tid;
  if (j < 96) {
    const float* wr = (j < 64) ? (Wpos + (size_t)j * 512)
                               : (Wner + (size_t)(j - 64) * 512);
    float b = (j < 64) ? bpos[j] : bner[j - 64];
    float acc = 0.f;
    for (int k = 0; k < 512; k += 4) {
      float4 wv = *(const float4*)(wr + k);
      acc += xv[k] * wv.x + xv[k + 1] * wv.y + xv[k + 2] * wv.z + xv[k + 3] * wv.w;
    }
    logit = acc + b;
    if (badf(logit)) { atomicOr(diag, 4); logit = 0.f; }
  }
  if (j < 64) {
    float m = logit;
    for (int o = 32; o >= 1; o >>= 1) m = fmaxf(m, __shfl_xor(m, o));
    float e = __expf(logit - m), sum = e;
    for (int o = 32; o >= 1; o >>= 1) sum += __shfl_xor(sum, o);
    float v = logit - m - logf(sum);
    if (!(v > -1e30f && v < 1e30f)) v = -111.f;
    dout[(size_t)s * 64 + j] = v;
  } else if (j < 96) {
    float m = logit;
    for (int o = 16; o >= 1; o >>= 1) m = fmaxf(m, __shfl_xor(m, o, 32));
    float e = __expf(logit - m), sum = e;
    for (int o = 16; o >= 1; o >>= 1) sum += __shfl_xor(sum, o, 32);
    float v = logit - m - logf(sum);
    if (!(v > -1e30f && v < 1e30f)) v = -111.f;
    dout[262144 + (size_t)s * 32 + (j - 64)] = v;
  }
}

// ---------------- diagnostics (silent when healthy)
__global__ void diag_k(const float* __restrict__ ce,
                       int* __restrict__ diag,
                       float* __restrict__ dout)
{
  int cnt = 0;
  for (int i = 0; i < 64; ++i) {
    float x = ce[i];
    if (x == x && fabsf(x) < 100.f) cnt++;
  }
  if (cnt < 48) diag[0] |= 8;
  int d = diag[0];
  if (d) dout[0] = 1000.f + 100.f * (float)d;
}

__global__ void wssmall_k(float* __restrict__ dout, int mb)
{
  dout[0] = 10000.f + (float)mb;
}

extern "C" void kernel_launch(void* const* d_in, const int* in_sizes, int n_in,
                              void* d_out, int out_size, void* d_ws, size_t ws_size,
                              hipStream_t stream) {
  const int*   word_seq  = (const int*)d_in[0];
  const int*   chars     = (const int*)d_in[1];
  const int*   char_lens = (const int*)d_in[2];
  const int*   feat_seq  = (const int*)d_in[3];
  const float* char_emb  = (const float*)d_in[4];
  const float* word_emb  = (const float*)d_in[5];
  const float* prefix_emb= (const float*)d_in[6];
  const float* Wih_c     = (const float*)d_in[7];
  const float* Whh_c     = (const float*)d_in[8];
  const float* bih_c     = (const float*)d_in[9];
  const float* bhh_c     = (const float*)d_in[10];
  const float* Wih_f     = (const float*)d_in[11];
  const float* Whh_f     = (const float*)d_in[12];
  const float* bih_f     = (const float*)d_in[13];
  const float* bhh_f     = (const float*)d_in[14];
  const float* Wih_b     = (const float*)d_in[15];
  const float* Whh_b     = (const float*)d_in[16];
  const float* bih_b     = (const float*)d_in[17];
  const float* bhh_b     = (const float*)d_in[18];
  const float* Wpos      = (const float*)d_in[19];
  const float* bpos      = (const float*)d_in[20];
  const float* Wner      = (const float*)d_in[21];
  const float* bner      = (const float*)d_in[22];
  float* dout = (float*)d_out;

  const size_t MB = 1048576;
  char* ws = (char*)d_ws;
  // small region
  int*            diag  = (int*)(ws + 512);           // 512 B
  float*          bias2 = (float*)(ws + 8192);        // 8 KB
  unsigned int*   Wpk   = (unsigned int*)(ws + 65536);// 1 MB, 16B-aligned
  // big region (phase-overlapped)
  unsigned short* hA    = (unsigned short*)(ws + 2 * MB);   // 4 MB [4096,512] bf16
  unsigned short* hB    = (unsigned short*)(ws + 6 * MB);   // 4 MB
  unsigned short* xUb   = (unsigned short*)(ws + 10 * MB);  // 2 MB [512,2048] bf16
  unsigned short* cb    = (unsigned short*)(ws + 12 * MB);  // 4 MB [4096,512] bf16

  const size_t NEED_A2 = 22 * MB;  // P_f 6..14, P_b 14..22 (both scans in parallel)
  const size_t NEED_B  = 16 * MB;  // sequential dir scans, shared P buffer
  unsigned short* P_f;
  unsigned short* P_b;
  unsigned short* out_f;
  unsigned short* out_b;
  int layoutA;
  if (ws_size >= NEED_A2) {
    layoutA = 1;
    P_f   = (unsigned short*)(ws + 6 * MB);    // over dead hB/xUb
    P_b   = (unsigned short*)(ws + 14 * MB);   // over dead cb + fresh
    out_f = (unsigned short*)(ws + 2 * MB);    // over dead hA
    out_b = (unsigned short*)(ws + 4 * MB);
  } else if (ws_size >= NEED_B) {
    layoutA = 0;
    P_f   = (unsigned short*)(ws + 6 * MB);
    P_b   = (unsigned short*)(ws + 6 * MB);
    out_f = (unsigned short*)(ws + 14 * MB);
    out_b = (unsigned short*)(ws + 2 * MB);
  } else {
    wssmall_k<<<1, 1, 0, stream>>>(dout, (int)(ws_size >> 20));
    return;
  }

  prep_xu_k<<<(512 * 2048) / 256, 256, 0, stream>>>(char_emb, Wih_c, bih_c, bhh_c, xUb);
  prep_h0c0_k<<<(4096 * 512) / 256, 256, 0, stream>>>(prefix_emb, feat_seq, hA, cb);
  prep_scanw2_k<<<(2 * 32 * 1024 * 4) / 256, 256, 0, stream>>>(
      Whh_f, Whh_b, bih_f, bhh_f, bih_b, bhh_b, Wpk, bias2, diag);

  unsigned short* hcur = hA;
  unsigned short* hnxt = hB;
  for (int t = 0; t < 16; ++t) {
    gemm_char_k<<<dim3(16, 32), 256, 0, stream>>>(
        hcur, Whh_c, xUb, chars, char_lens, t, hnxt, cb, diag);
    unsigned short* tmp = hcur; hcur = hnxt; hnxt = tmp;
  }
  // after 16 swaps, final char features are in hA (hcur == hA)

  if (layoutA) {
    gemm_gather_nt_k<<<dim3(8, 32), 256, 0, stream>>>(word_emb, word_seq, hcur, Wih_f, P_f);
    gemm_gather_nt_k<<<dim3(8, 32), 256, 0, stream>>>(word_emb, word_seq, hcur, Wih_b, P_b);
    scan2_k<<<2, 512, 0, stream>>>(P_f, P_b, Wpk, bias2, out_f, out_b, diag, -1);
  } else {
    gemm_gather_nt_k<<<dim3(8, 32), 256, 0, stream>>>(word_emb, word_seq, hcur, Wih_f, P_f);
    scan2_k<<<1, 512, 0, stream>>>(P_f, P_b, Wpk, bias2, out_f, out_b, diag, 0);
    gemm_gather_nt_k<<<dim3(8, 32), 256, 0, stream>>>(word_emb, word_seq, hcur, Wih_b, P_b);
    scan2_k<<<1, 512, 0, stream>>>(P_f, P_b, Wpk, bias2, out_f, out_b, diag, 1);
  }

  head_k<<<4096, 128, 0, stream>>>(out_f, out_b, Wpos, bpos, Wner, bner, dout, diag);

  diag_k<<<1, 1, 0, stream>>>(char_emb, diag, dout);
}

// Round 3
// 9242.154 us; speedup vs baseline: 1.0301x; 1.0301x over previous
//
#include <hip/hip_runtime.h>

#define SS 4096
#define LL 16
#define HD 512
#define ECD 128
#define HHD 256

typedef __attribute__((ext_vector_type(8))) short short8;
typedef __attribute__((ext_vector_type(4))) float float4v;
typedef _Float16 half2v __attribute__((ext_vector_type(2)));

__device__ __forceinline__ float bf2f(unsigned short u){
  union { unsigned int i; float f; } v; v.i = ((unsigned int)u) << 16; return v.f;
}
__device__ __forceinline__ unsigned short f2bf(float f){
  union { float f; unsigned int i; } v; v.f = f;
  unsigned int u = v.i;
  unsigned int r = (u + 0x7fffu + ((u >> 16) & 1u)) >> 16;
  return (unsigned short)r;
}
__device__ __forceinline__ unsigned short f2h(float x){
  _Float16 h = (_Float16)x;
  return __builtin_bit_cast(unsigned short, h);
}
__device__ __forceinline__ float sigf(float x){ return 1.f / (1.f + __expf(-x)); }
__device__ __forceinline__ float tanh_f(float x){
  float e = __expf(2.f * x);
  return 1.f - 2.f / (e + 1.f);
}
__device__ __forceinline__ float fdot2u(unsigned int a, unsigned int b, float c){
  half2v ha = __builtin_bit_cast(half2v, a);
  half2v hb = __builtin_bit_cast(half2v, b);
#if __has_builtin(__builtin_amdgcn_fdot2)
  return __builtin_amdgcn_fdot2(ha, hb, c, false);
#else
  return c + (float)ha[0]*(float)hb[0] + (float)ha[1]*(float)hb[1];
#endif
}
__device__ __forceinline__ unsigned int packf16(float lo, float hi){
  half2v h; h[0] = (_Float16)lo; h[1] = (_Float16)hi;
  return __builtin_bit_cast(unsigned int, h);
}
__device__ __forceinline__ bool badf(float x){ return !(fabsf(x) < 1e30f); }

// pack 8 f32 -> 8 bf16 (as int4) for LDS staging
__device__ __forceinline__ int4 cvt8(const float* __restrict__ s){
  union { unsigned short u[8]; int4 v; } pk;
#pragma unroll
  for (int i = 0; i < 8; ++i) pk.u[i] = f2bf(s[i]);
  return pk.v;
}

// ---------------- prep: xUb[c][n] = char_emb[c].Wih_c[n] + bih_c[n] + bhh_c[n]  (bf16 out)
__global__ void prep_xu_k(const float* __restrict__ char_emb,
                          const float* __restrict__ Wih_c,
                          const float* __restrict__ bih_c,
                          const float* __restrict__ bhh_c,
                          unsigned short* __restrict__ xUb)
{
  int idx = blockIdx.x * 256 + threadIdx.x;   // 512 * 2048
  int c = idx >> 11, n = idx & 2047;
  const float* ce = char_emb + (size_t)c * ECD;
  const float* wr = Wih_c + (size_t)n * ECD;
  float acc = bih_c[n] + bhh_c[n];
  for (int k = 0; k < ECD; k += 4) {
    float4 a = *(const float4*)(ce + k);
    float4 b = *(const float4*)(wr + k);
    acc += a.x*b.x + a.y*b.y + a.z*b.z + a.w*b.w;
  }
  xUb[idx] = f2bf(acc);
}

// ---------------- prep: h0 = prefix_emb[feat_seq] (bf16), c0 = 0 (bf16)
__global__ void prep_h0c0_k(const float* __restrict__ prefix_emb,
                            const int* __restrict__ feat_seq,
                            unsigned short* __restrict__ h0,
                            unsigned short* __restrict__ c0)
{
  int idx = blockIdx.x * 256 + threadIdx.x;  // 4096*512
  int s = idx >> 9, j = idx & 511;
  h0[idx] = f2bf(prefix_emb[(size_t)feat_seq[s] * HD + j]);
  c0[idx] = 0;
}

// ---------------- prep v2: pack Whh_{f,b} (f32) into [dir][q4 0..31][row 0..1023][j 0..3] u32 f16x2
// u32 index = (dir<<17) | (q4<<12) | (row<<2) | j ; covers k = 2*(q4*4+j), +1
__global__ void prep_scanw2_k(const float* __restrict__ Whh_f,
                              const float* __restrict__ Whh_b,
                              const float* __restrict__ bih_f,
                              const float* __restrict__ bhh_f,
                              const float* __restrict__ bih_b,
                              const float* __restrict__ bhh_b,
                              unsigned int* __restrict__ Wpk,
                              float* __restrict__ biasbuf,
                              int* __restrict__ diag)
{
  int idx = blockIdx.x * 256 + threadIdx.x;  // 2*32*1024*4 = 262144
  int j   = idx & 3;
  int row = (idx >> 2) & 1023;
  int q4  = (idx >> 12) & 31;
  int dir = (idx >> 17) & 1;
  int k = 2 * (q4 * 4 + j);
  const float* W = dir ? Whh_b : Whh_f;   // [1024,256] f32, rows gate-major i,f,g,o
  Wpk[idx] = packf16(W[(size_t)row * HHD + k], W[(size_t)row * HHD + k + 1]);
  if (idx < 2048) {
    int dr = idx >> 10, g = idx & 1023;
    biasbuf[idx] = dr ? (bih_b[g] + bhh_b[g]) : (bih_f[g] + bhh_f[g]);
  }
  if (idx == 0) diag[0] = 0;
}

// ---------------- fused char-step: gates = h_in @ Whh_c^T (MFMA), then LSTM cell epilogue
__global__ __launch_bounds__(256) void gemm_char_k(
    const unsigned short* __restrict__ hin,   // [4096,512] bf16
    const float* __restrict__ Whh,            // [2048,512] f32
    const unsigned short* __restrict__ xUb,   // [512,2048] bf16
    const int* __restrict__ chars,
    const int* __restrict__ lens,
    int t,
    unsigned short* __restrict__ hout,        // [4096,512] bf16
    unsigned short* __restrict__ cb,          // [4096,512] bf16 (in/out)
    int* __restrict__ diag)
{
  __shared__ __align__(16) unsigned short As[128 * 32];
  __shared__ __align__(16) unsigned short Bs[128 * 32];
  __shared__ __align__(16) unsigned short gates[128 * 136];
  const int tid = threadIdx.x;
  const int m0 = blockIdx.y * 128;
  const int n0h = blockIdx.x * 32;            // base h-column of this tile
  const int wave = tid >> 6;
  const int lane = tid & 63;
  const int wm = (wave >> 1) * 64;
  const int wn = (wave & 1) * 64;
  float4v z = {0.f, 0.f, 0.f, 0.f};
  float4v acc[4][4];
#pragma unroll
  for (int i = 0; i < 4; ++i)
#pragma unroll
    for (int j = 0; j < 4; ++j) acc[i][j] = z;

  for (int k0 = 0; k0 < 512; k0 += 32) {
    __syncthreads();
#pragma unroll
    for (int i = 0; i < 2; ++i) {
      int chunk = tid * 2 + i;           // 0..511
      int row = chunk >> 2;              // 0..127
      int k8 = (chunk & 3) * 8;
      int4 av = *(const int4*)(hin + (size_t)(m0 + row) * 512 + k0 + k8);
      *(int4*)(As + row * 32 + k8) = av;
      int br = (row >> 5) * 512 + n0h + (row & 31);
      *(int4*)(Bs + row * 32 + k8) = cvt8(Whh + (size_t)br * 512 + k0 + k8);
    }
    __syncthreads();
    short8 af[4], bfr[4];
    const int kq = (lane >> 4) * 8;
#pragma unroll
    for (int i = 0; i < 4; ++i) {
      af[i]  = *(const short8*)(As + (wm + i * 16 + (lane & 15)) * 32 + kq);
      bfr[i] = *(const short8*)(Bs + (wn + i * 16 + (lane & 15)) * 32 + kq);
    }
#pragma unroll
    for (int i = 0; i < 4; ++i)
#pragma unroll
      for (int j = 0; j < 4; ++j)
        acc[i][j] = __builtin_amdgcn_mfma_f32_16x16x32_bf16(af[i], bfr[j], acc[i][j], 0, 0, 0);
  }
  __syncthreads();
#pragma unroll
  for (int i = 0; i < 4; ++i)
#pragma unroll
    for (int j = 0; j < 4; ++j)
#pragma unroll
      for (int r = 0; r < 4; ++r) {
        int row = wm + i * 16 + (lane >> 4) * 4 + r;
        int col = wn + j * 16 + (lane & 15);
        gates[row * 136 + col] = f2bf(acc[i][j][r]);
      }
  __syncthreads();
#pragma unroll
  for (int e = 0; e < 16; ++e) {
    int idx = e * 256 + tid;
    int r = idx >> 5, hc = idx & 31;
    int s = m0 + r;
    int col = n0h + hc;
    if (t < lens[s]) {
      int cid = chars[s * LL + t];
      size_t xb = (size_t)cid * 2048 + col;
      float gi = bf2f(gates[r * 136 + hc])      + bf2f(xUb[xb]);
      float gf = bf2f(gates[r * 136 + 32 + hc]) + bf2f(xUb[xb + 512]);
      float gg = bf2f(gates[r * 136 + 64 + hc]) + bf2f(xUb[xb + 1024]);
      float go = bf2f(gates[r * 136 + 96 + hc]) + bf2f(xUb[xb + 1536]);
      if (badf(gi + gf + gg + go)) atomicOr(diag, 1);
      float cc = sigf(gf) * bf2f(cb[(size_t)s * 512 + col]) + sigf(gi) * tanh_f(gg);
      cb[(size_t)s * 512 + col] = f2bf(cc);
      hout[(size_t)s * 512 + col] = f2bf(sigf(go) * tanh_f(cc));
    } else {
      hout[(size_t)s * 512 + col] = hin[(size_t)s * 512 + col];
    }
  }
}

// ---------------- P GEMM: P[M=4096, N=1024](bf16) = [word_emb[wseq] f32 | h bf16] @ Wih^T(f32)
__global__ __launch_bounds__(256) void gemm_gather_nt_k(
    const float* __restrict__ wemb,
    const int* __restrict__ wseq,
    const unsigned short* __restrict__ hbuf,
    const float* __restrict__ B,              // [1024,1024] f32
    unsigned short* __restrict__ P)           // [4096,1024] bf16
{
  __shared__ __align__(16) unsigned short As[128 * 32];
  __shared__ __align__(16) unsigned short Bs[128 * 32];
  const int tid = threadIdx.x;
  const int m0 = blockIdx.y * 128;
  const int n0 = blockIdx.x * 128;
  const int wave = tid >> 6;
  const int lane = tid & 63;
  const int wm = (wave >> 1) * 64;
  const int wn = (wave & 1) * 64;
  float4v z = {0.f, 0.f, 0.f, 0.f};
  float4v acc[4][4];
#pragma unroll
  for (int i = 0; i < 4; ++i)
#pragma unroll
    for (int j = 0; j < 4; ++j) acc[i][j] = z;

  for (int k0 = 0; k0 < 1024; k0 += 32) {
    __syncthreads();
#pragma unroll
    for (int i = 0; i < 2; ++i) {
      int chunk = tid * 2 + i;
      int row = chunk >> 2;
      int k8 = (chunk & 3) * 8;
      int arow = m0 + row;
      int acol = k0 + k8;
      if (acol < 512) {
        *(int4*)(As + row * 32 + k8) = cvt8(wemb + (size_t)wseq[arow] * 512 + acol);
      } else {
        int4 av = *(const int4*)(hbuf + (size_t)arow * 512 + (acol - 512));
        *(int4*)(As + row * 32 + k8) = av;
      }
      *(int4*)(Bs + row * 32 + k8) = cvt8(B + (size_t)(n0 + row) * 1024 + k0 + k8);
    }
    __syncthreads();
    short8 af[4], bfr[4];
    const int kq = (lane >> 4) * 8;
#pragma unroll
    for (int i = 0; i < 4; ++i) {
      af[i]  = *(const short8*)(As + (wm + i * 16 + (lane & 15)) * 32 + kq);
      bfr[i] = *(const short8*)(Bs + (wn + i * 16 + (lane & 15)) * 32 + kq);
    }
#pragma unroll
    for (int i = 0; i < 4; ++i)
#pragma unroll
      for (int j = 0; j < 4; ++j)
        acc[i][j] = __builtin_amdgcn_mfma_f32_16x16x32_bf16(af[i], bfr[j], acc[i][j], 0, 0, 0);
  }
#pragma unroll
  for (int i = 0; i < 4; ++i)
#pragma unroll
    for (int j = 0; j < 4; ++j)
#pragma unroll
      for (int r = 0; r < 4; ++r) {
        int row = m0 + wm + i * 16 + (lane >> 4) * 4 + r;
        int col = n0 + wn + j * 16 + (lane & 15);
        P[(size_t)row * 1024 + col] = f2bf(acc[i][j][r]);
      }
}

// ---------------- scan v3: ONE block per direction; weights 24 chunk-pairs in VGPR
// (192 regs, total pressure ~236 < 256 cap @ 2 waves/SIMD) + 8 chunk-pairs in LDS
// (128 KB). h/c/g state in LDS; 2 barriers/step; branchless P prefetch.
__global__ __launch_bounds__(512, 2) void scan3_k(
    const unsigned short* __restrict__ P_f,   // [4096,1024] bf16
    const unsigned short* __restrict__ P_b,
    const unsigned int* __restrict__ Wpk,     // [2][32][1024][4] u32 (f16x2)
    const float* __restrict__ biasbuf,        // [2][1024] f32
    unsigned short* __restrict__ out_f,       // [4096,256] bf16
    unsigned short* __restrict__ out_b,
    int* __restrict__ diag, int dirsel)
{
  const int dir = (dirsel < 0) ? (int)blockIdx.x : dirsel;
  const int tid = threadIdx.x;
  const int rA = tid;          // rows 0..511   (gate i: 0..255, gate f: 256..511)
  const int rB = tid + 512;    // rows 512..1023 (gate g, gate o)

  __shared__ __align__(16) uint4 ldsW[8 * 1024];          // 128 KB: chunks q4=24..31
  __shared__ __align__(16) float g_lds[1024];
  __shared__ __align__(16) float c_lds[256];
  __shared__ __align__(16) unsigned short h16[256];       // f16 h state (32 uint4)

  const uint4* wp = (const uint4*)Wpk + (size_t)dir * 32 * 1024;
  uint4 wA[24], wB[24];
#pragma unroll
  for (int q4 = 0; q4 < 24; ++q4) {
    wA[q4] = wp[q4 * 1024 + rA];
    wB[q4] = wp[q4 * 1024 + rB];
  }
#pragma unroll
  for (int q4 = 24; q4 < 32; ++q4) {
    ldsW[(q4 - 24) * 1024 + rA] = wp[q4 * 1024 + rA];
    ldsW[(q4 - 24) * 1024 + rB] = wp[q4 * 1024 + rB];
  }
  // no-op keepalive: pin weight values as VGPR-resident at loop entry
#pragma unroll
  for (int q4 = 0; q4 < 24; ++q4) {
    asm volatile("" : "+v"(wA[q4].x), "+v"(wA[q4].y), "+v"(wA[q4].z), "+v"(wA[q4].w));
    asm volatile("" : "+v"(wB[q4].x), "+v"(wB[q4].y), "+v"(wB[q4].z), "+v"(wB[q4].w));
  }
  const float bA = biasbuf[dir * 1024 + rA];
  const float bB = biasbuf[dir * 1024 + rB];
  const unsigned short* P = dir ? P_b : P_f;
  unsigned short* out = dir ? out_b : out_f;

  if (tid < 256) { h16[tid] = 0; c_lds[tid] = 0.f; }
  __syncthreads();

  // P prefetch for t=0
  int srow0 = dir ? 4095 : 0;
  float pA = bf2f(P[(size_t)srow0 * 1024 + rA]);
  float pB = bf2f(P[(size_t)srow0 * 1024 + rB]);

  for (int t = 0; t < 4096; ++t) {
    const int srow = dir ? (4095 - t) : t;
    // branchless prefetch of next-step P (wraps harmlessly at the end)
    const int nrow = dir ? ((4094 - t) & 4095) : ((t + 1) & 4095);
    float npA = bf2f(P[(size_t)nrow * 1024 + rA]);
    float npB = bf2f(P[(size_t)nrow * 1024 + rB]);

    float accA = 0.f, accB = 0.f;
    const uint4* h4 = (const uint4*)h16;   // 32 broadcast chunks of 8 f16
#pragma unroll
    for (int q4 = 0; q4 < 24; ++q4) {
      uint4 hv = h4[q4];
      accA = fdot2u(wA[q4].x, hv.x, accA);
      accA = fdot2u(wA[q4].y, hv.y, accA);
      accA = fdot2u(wA[q4].z, hv.z, accA);
      accA = fdot2u(wA[q4].w, hv.w, accA);
      accB = fdot2u(wB[q4].x, hv.x, accB);
      accB = fdot2u(wB[q4].y, hv.y, accB);
      accB = fdot2u(wB[q4].z, hv.z, accB);
      accB = fdot2u(wB[q4].w, hv.w, accB);
    }
#pragma unroll
    for (int q4 = 24; q4 < 32; ++q4) {
      uint4 hv = h4[q4];
      uint4 wa = ldsW[(q4 - 24) * 1024 + rA];
      uint4 wb = ldsW[(q4 - 24) * 1024 + rB];
      accA = fdot2u(wa.x, hv.x, accA);
      accA = fdot2u(wa.y, hv.y, accA);
      accA = fdot2u(wa.z, hv.z, accA);
      accA = fdot2u(wa.w, hv.w, accA);
      accB = fdot2u(wb.x, hv.x, accB);
      accB = fdot2u(wb.y, hv.y, accB);
      accB = fdot2u(wb.z, hv.z, accB);
      accB = fdot2u(wb.w, hv.w, accB);
    }
    g_lds[rA] = accA + bA + pA;
    g_lds[rB] = accB + bB + pB;
    __syncthreads();            // gates ready; h16 fully consumed
    if (tid < 256) {
      float gi = g_lds[tid];
      float gf = g_lds[256 + tid];
      float gg = g_lds[512 + tid];
      float go = g_lds[768 + tid];
      if (badf(gi + gf + gg + go)) atomicOr(diag, 2);
      float cc = sigf(gf) * c_lds[tid] + sigf(gi) * tanh_f(gg);
      float hh = sigf(go) * tanh_f(cc);
      c_lds[tid] = cc;
      h16[tid] = f2h(hh);
      out[(size_t)srow * HHD + tid] = f2bf(hh);
    }
    pA = npA; pB = npB;
    __syncthreads();            // new h16 ready
  }
}

// ---------------- heads: logits + log_softmax -> f32 out
__global__ __launch_bounds__(128) void head_k(
    const unsigned short* __restrict__ out_f, const unsigned short* __restrict__ out_b,
    const float* __restrict__ Wpos, const float* __restrict__ bpos,
    const float* __restrict__ Wner, const float* __restrict__ bner,
    float* __restrict__ dout, int* __restrict__ diag)
{
  const int s = blockIdx.x, tid = threadIdx.x;
  __shared__ __align__(16) float xv[512];
#pragma unroll
  for (int i = 0; i < 4; ++i) {
    int k = tid * 4 + i;
    xv[k] = (k < 256) ? bf2f(out_f[(size_t)s * 256 + k])
                      : bf2f(out_b[(size_t)s * 256 + (k - 256)]);
  }
  __syncthreads();
  float logit = 0.f;
  const int j = tid;
  if (j < 96) {
    const float* wr = (j < 64) ? (Wpos + (size_t)j * 512)
                               : (Wner + (size_t)(j - 64) * 512);
    float b = (j < 64) ? bpos[j] : bner[j - 64];
    float acc = 0.f;
    for (int k = 0; k < 512; k += 4) {
      float4 wv = *(const float4*)(wr + k);
      acc += xv[k] * wv.x + xv[k + 1] * wv.y + xv[k + 2] * wv.z + xv[k + 3] * wv.w;
    }
    logit = acc + b;
    if (badf(logit)) { atomicOr(diag, 4); logit = 0.f; }
  }
  if (j < 64) {
    float m = logit;
    for (int o = 32; o >= 1; o >>= 1) m = fmaxf(m, __shfl_xor(m, o));
    float e = __expf(logit - m), sum = e;
    for (int o = 32; o >= 1; o >>= 1) sum += __shfl_xor(sum, o);
    float v = logit - m - logf(sum);
    if (!(v > -1e30f && v < 1e30f)) v = -111.f;
    dout[(size_t)s * 64 + j] = v;
  } else if (j < 96) {
    float m = logit;
    for (int o = 16; o >= 1; o >>= 1) m = fmaxf(m, __shfl_xor(m, o, 32));
    float e = __expf(logit - m), sum = e;
    for (int o = 16; o >= 1; o >>= 1) sum += __shfl_xor(sum, o, 32);
    float v = logit - m - logf(sum);
    if (!(v > -1e30f && v < 1e30f)) v = -111.f;
    dout[262144 + (size_t)s * 32 + (j - 64)] = v;
  }
}

// ---------------- diagnostics (silent when healthy)
__global__ void diag_k(const float* __restrict__ ce,
                       int* __restrict__ diag,
                       float* __restrict__ dout)
{
  int cnt = 0;
  for (int i = 0; i < 64; ++i) {
    float x = ce[i];
    if (x == x && fabsf(x) < 100.f) cnt++;
  }
  if (cnt < 48) diag[0] |= 8;
  int d = diag[0];
  if (d) dout[0] = 1000.f + 100.f * (float)d;
}

__global__ void wssmall_k(float* __restrict__ dout, int mb)
{
  dout[0] = 10000.f + (float)mb;
}

extern "C" void kernel_launch(void* const* d_in, const int* in_sizes, int n_in,
                              void* d_out, int out_size, void* d_ws, size_t ws_size,
                              hipStream_t stream) {
  const int*   word_seq  = (const int*)d_in[0];
  const int*   chars     = (const int*)d_in[1];
  const int*   char_lens = (const int*)d_in[2];
  const int*   feat_seq  = (const int*)d_in[3];
  const float* char_emb  = (const float*)d_in[4];
  const float* word_emb  = (const float*)d_in[5];
  const float* prefix_emb= (const float*)d_in[6];
  const float* Wih_c     = (const float*)d_in[7];
  const float* Whh_c     = (const float*)d_in[8];
  const float* bih_c     = (const float*)d_in[9];
  const float* bhh_c     = (const float*)d_in[10];
  const float* Wih_f     = (const float*)d_in[11];
  const float* Whh_f     = (const float*)d_in[12];
  const float* bih_f     = (const float*)d_in[13];
  const float* bhh_f     = (const float*)d_in[14];
  const float* Wih_b     = (const float*)d_in[15];
  const float* Whh_b     = (const float*)d_in[16];
  const float* bih_b     = (const float*)d_in[17];
  const float* bhh_b     = (const float*)d_in[18];
  const float* Wpos      = (const float*)d_in[19];
  const float* bpos      = (const float*)d_in[20];
  const float* Wner      = (const float*)d_in[21];
  const float* bner      = (const float*)d_in[22];
  float* dout = (float*)d_out;

  const size_t MB = 1048576;
  char* ws = (char*)d_ws;
  // small region
  int*            diag  = (int*)(ws + 512);           // 512 B
  float*          bias2 = (float*)(ws + 8192);        // 8 KB
  unsigned int*   Wpk   = (unsigned int*)(ws + 65536);// 1 MB, 16B-aligned
  // big region (phase-overlapped)
  unsigned short* hA    = (unsigned short*)(ws + 2 * MB);   // 4 MB [4096,512] bf16
  unsigned short* hB    = (unsigned short*)(ws + 6 * MB);   // 4 MB
  unsigned short* xUb   = (unsigned short*)(ws + 10 * MB);  // 2 MB [512,2048] bf16
  unsigned short* cb    = (unsigned short*)(ws + 12 * MB);  // 4 MB [4096,512] bf16

  const size_t NEED_A2 = 22 * MB;  // P_f 6..14, P_b 14..22 (both scans in parallel)
  const size_t NEED_B  = 16 * MB;  // sequential dir scans, shared P buffer
  unsigned short* P_f;
  unsigned short* P_b;
  unsigned short* out_f;
  unsigned short* out_b;
  int layoutA;
  if (ws_size >= NEED_A2) {
    layoutA = 1;
    P_f   = (unsigned short*)(ws + 6 * MB);    // over dead hB/xUb
    P_b   = (unsigned short*)(ws + 14 * MB);   // over dead cb + fresh
    out_f = (unsigned short*)(ws + 2 * MB);    // over dead hA
    out_b = (unsigned short*)(ws + 4 * MB);
  } else if (ws_size >= NEED_B) {
    layoutA = 0;
    P_f   = (unsigned short*)(ws + 6 * MB);
    P_b   = (unsigned short*)(ws + 6 * MB);
    out_f = (unsigned short*)(ws + 14 * MB);
    out_b = (unsigned short*)(ws + 2 * MB);
  } else {
    wssmall_k<<<1, 1, 0, stream>>>(dout, (int)(ws_size >> 20));
    return;
  }

  prep_xu_k<<<(512 * 2048) / 256, 256, 0, stream>>>(char_emb, Wih_c, bih_c, bhh_c, xUb);
  prep_h0c0_k<<<(4096 * 512) / 256, 256, 0, stream>>>(prefix_emb, feat_seq, hA, cb);
  prep_scanw2_k<<<(2 * 32 * 1024 * 4) / 256, 256, 0, stream>>>(
      Whh_f, Whh_b, bih_f, bhh_f, bih_b, bhh_b, Wpk, bias2, diag);

  unsigned short* hcur = hA;
  unsigned short* hnxt = hB;
  for (int t = 0; t < 16; ++t) {
    gemm_char_k<<<dim3(16, 32), 256, 0, stream>>>(
        hcur, Whh_c, xUb, chars, char_lens, t, hnxt, cb, diag);
    unsigned short* tmp = hcur; hcur = hnxt; hnxt = tmp;
  }
  // after 16 swaps, final char features are in hA (hcur == hA)

  if (layoutA) {
    gemm_gather_nt_k<<<dim3(8, 32), 256, 0, stream>>>(word_emb, word_seq, hcur, Wih_f, P_f);
    gemm_gather_nt_k<<<dim3(8, 32), 256, 0, stream>>>(word_emb, word_seq, hcur, Wih_b, P_b);
    scan3_k<<<2, 512, 0, stream>>>(P_f, P_b, Wpk, bias2, out_f, out_b, diag, -1);
  } else {
    gemm_gather_nt_k<<<dim3(8, 32), 256, 0, stream>>>(word_emb, word_seq, hcur, Wih_f, P_f);
    scan3_k<<<1, 512, 0, stream>>>(P_f, P_b, Wpk, bias2, out_f, out_b, diag, 0);
    gemm_gather_nt_k<<<dim3(8, 32), 256, 0, stream>>>(word_emb, word_seq, hcur, Wih_b, P_b);
    scan3_k<<<1, 512, 0, stream>>>(P_f, P_b, Wpk, bias2, out_f, out_b, diag, 1);
  }

  head_k<<<4096, 128, 0, stream>>>(out_f, out_b, Wpos, bpos, Wner, bner, dout, diag);

  diag_k<<<1, 1, 0, stream>>>(char_emb, diag, dout);
}

// Round 4
// 8429.871 us; speedup vs baseline: 1.1294x; 1.0964x over previous
//
#include <hip/hip_runtime.h>

#define SS 4096
#define LL 16
#define HD 512
#define ECD 128
#define HHD 256

typedef __attribute__((ext_vector_type(8))) short short8;
typedef __attribute__((ext_vector_type(4))) float float4v;
typedef _Float16 half2v __attribute__((ext_vector_type(2)));

__device__ __forceinline__ float bf2f(unsigned short u){
  union { unsigned int i; float f; } v; v.i = ((unsigned int)u) << 16; return v.f;
}
__device__ __forceinline__ unsigned short f2bf(float f){
  union { float f; unsigned int i; } v; v.f = f;
  unsigned int u = v.i;
  unsigned int r = (u + 0x7fffu + ((u >> 16) & 1u)) >> 16;
  return (unsigned short)r;
}
__device__ __forceinline__ unsigned short f2h(float x){
  _Float16 h = (_Float16)x;
  return __builtin_bit_cast(unsigned short, h);
}
__device__ __forceinline__ float sigf(float x){ return 1.f / (1.f + __expf(-x)); }
__device__ __forceinline__ float tanh_f(float x){
  float e = __expf(2.f * x);
  return 1.f - 2.f / (e + 1.f);
}
__device__ __forceinline__ float fdot2u(unsigned int a, unsigned int b, float c){
  half2v ha = __builtin_bit_cast(half2v, a);
  half2v hb = __builtin_bit_cast(half2v, b);
#if __has_builtin(__builtin_amdgcn_fdot2)
  return __builtin_amdgcn_fdot2(ha, hb, c, false);
#else
  return c + (float)ha[0]*(float)hb[0] + (float)ha[1]*(float)hb[1];
#endif
}
__device__ __forceinline__ unsigned int packf16(float lo, float hi){
  half2v h; h[0] = (_Float16)lo; h[1] = (_Float16)hi;
  return __builtin_bit_cast(unsigned int, h);
}
__device__ __forceinline__ bool badf(float x){ return !(fabsf(x) < 1e30f); }

// pack 8 f32 -> 8 bf16 (as int4) for LDS staging
__device__ __forceinline__ int4 cvt8(const float* __restrict__ s){
  union { unsigned short u[8]; int4 v; } pk;
#pragma unroll
  for (int i = 0; i < 8; ++i) pk.u[i] = f2bf(s[i]);
  return pk.v;
}

// ---------------- prep: xUb[c][n] = char_emb[c].Wih_c[n] + bih_c[n] + bhh_c[n]  (bf16 out)
__global__ void prep_xu_k(const float* __restrict__ char_emb,
                          const float* __restrict__ Wih_c,
                          const float* __restrict__ bih_c,
                          const float* __restrict__ bhh_c,
                          unsigned short* __restrict__ xUb)
{
  int idx = blockIdx.x * 256 + threadIdx.x;   // 512 * 2048
  int c = idx >> 11, n = idx & 2047;
  const float* ce = char_emb + (size_t)c * ECD;
  const float* wr = Wih_c + (size_t)n * ECD;
  float acc = bih_c[n] + bhh_c[n];
  for (int k = 0; k < ECD; k += 4) {
    float4 a = *(const float4*)(ce + k);
    float4 b = *(const float4*)(wr + k);
    acc += a.x*b.x + a.y*b.y + a.z*b.z + a.w*b.w;
  }
  xUb[idx] = f2bf(acc);
}

// ---------------- prep: h0 = prefix_emb[feat_seq] (bf16), c0 = 0 (bf16)
__global__ void prep_h0c0_k(const float* __restrict__ prefix_emb,
                            const int* __restrict__ feat_seq,
                            unsigned short* __restrict__ h0,
                            unsigned short* __restrict__ c0)
{
  int idx = blockIdx.x * 256 + threadIdx.x;  // 4096*512
  int s = idx >> 9, j = idx & 511;
  h0[idx] = f2bf(prefix_emb[(size_t)feat_seq[s] * HD + j]);
  c0[idx] = 0;
}

// ---------------- prep v2: pack Whh_{f,b} (f32) into [dir][q4 0..31][row 0..1023][j 0..3] u32 f16x2
// u32 index = (dir<<17) | (q4<<12) | (row<<2) | j ; covers k = 2*(q4*4+j), +1
__global__ void prep_scanw2_k(const float* __restrict__ Whh_f,
                              const float* __restrict__ Whh_b,
                              const float* __restrict__ bih_f,
                              const float* __restrict__ bhh_f,
                              const float* __restrict__ bih_b,
                              const float* __restrict__ bhh_b,
                              unsigned int* __restrict__ Wpk,
                              float* __restrict__ biasbuf,
                              int* __restrict__ diag)
{
  int idx = blockIdx.x * 256 + threadIdx.x;  // 2*32*1024*4 = 262144
  int j   = idx & 3;
  int row = (idx >> 2) & 1023;
  int q4  = (idx >> 12) & 31;
  int dir = (idx >> 17) & 1;
  int k = 2 * (q4 * 4 + j);
  const float* W = dir ? Whh_b : Whh_f;   // [1024,256] f32, rows gate-major i,f,g,o
  Wpk[idx] = packf16(W[(size_t)row * HHD + k], W[(size_t)row * HHD + k + 1]);
  if (idx < 2048) {
    int dr = idx >> 10, g = idx & 1023;
    biasbuf[idx] = dr ? (bih_b[g] + bhh_b[g]) : (bih_f[g] + bhh_f[g]);
  }
  if (idx == 0) diag[0] = 0;
}

// ---------------- fused char-step: gates = h_in @ Whh_c^T (MFMA), then LSTM cell epilogue
__global__ __launch_bounds__(256) void gemm_char_k(
    const unsigned short* __restrict__ hin,   // [4096,512] bf16
    const float* __restrict__ Whh,            // [2048,512] f32
    const unsigned short* __restrict__ xUb,   // [512,2048] bf16
    const int* __restrict__ chars,
    const int* __restrict__ lens,
    int t,
    unsigned short* __restrict__ hout,        // [4096,512] bf16
    unsigned short* __restrict__ cb,          // [4096,512] bf16 (in/out)
    int* __restrict__ diag)
{
  __shared__ __align__(16) unsigned short As[128 * 32];
  __shared__ __align__(16) unsigned short Bs[128 * 32];
  __shared__ __align__(16) unsigned short gates[128 * 136];
  const int tid = threadIdx.x;
  const int m0 = blockIdx.y * 128;
  const int n0h = blockIdx.x * 32;            // base h-column of this tile
  const int wave = tid >> 6;
  const int lane = tid & 63;
  const int wm = (wave >> 1) * 64;
  const int wn = (wave & 1) * 64;
  float4v z = {0.f, 0.f, 0.f, 0.f};
  float4v acc[4][4];
#pragma unroll
  for (int i = 0; i < 4; ++i)
#pragma unroll
    for (int j = 0; j < 4; ++j) acc[i][j] = z;

  for (int k0 = 0; k0 < 512; k0 += 32) {
    __syncthreads();
#pragma unroll
    for (int i = 0; i < 2; ++i) {
      int chunk = tid * 2 + i;           // 0..511
      int row = chunk >> 2;              // 0..127
      int k8 = (chunk & 3) * 8;
      int4 av = *(const int4*)(hin + (size_t)(m0 + row) * 512 + k0 + k8);
      *(int4*)(As + row * 32 + k8) = av;
      int br = (row >> 5) * 512 + n0h + (row & 31);
      *(int4*)(Bs + row * 32 + k8) = cvt8(Whh + (size_t)br * 512 + k0 + k8);
    }
    __syncthreads();
    short8 af[4], bfr[4];
    const int kq = (lane >> 4) * 8;
#pragma unroll
    for (int i = 0; i < 4; ++i) {
      af[i]  = *(const short8*)(As + (wm + i * 16 + (lane & 15)) * 32 + kq);
      bfr[i] = *(const short8*)(Bs + (wn + i * 16 + (lane & 15)) * 32 + kq);
    }
#pragma unroll
    for (int i = 0; i < 4; ++i)
#pragma unroll
      for (int j = 0; j < 4; ++j)
        acc[i][j] = __builtin_amdgcn_mfma_f32_16x16x32_bf16(af[i], bfr[j], acc[i][j], 0, 0, 0);
  }
  __syncthreads();
#pragma unroll
  for (int i = 0; i < 4; ++i)
#pragma unroll
    for (int j = 0; j < 4; ++j)
#pragma unroll
      for (int r = 0; r < 4; ++r) {
        int row = wm + i * 16 + (lane >> 4) * 4 + r;
        int col = wn + j * 16 + (lane & 15);
        gates[row * 136 + col] = f2bf(acc[i][j][r]);
      }
  __syncthreads();
#pragma unroll
  for (int e = 0; e < 16; ++e) {
    int idx = e * 256 + tid;
    int r = idx >> 5, hc = idx & 31;
    int s = m0 + r;
    int col = n0h + hc;
    if (t < lens[s]) {
      int cid = chars[s * LL + t];
      size_t xb = (size_t)cid * 2048 + col;
      float gi = bf2f(gates[r * 136 + hc])      + bf2f(xUb[xb]);
      float gf = bf2f(gates[r * 136 + 32 + hc]) + bf2f(xUb[xb + 512]);
      float gg = bf2f(gates[r * 136 + 64 + hc]) + bf2f(xUb[xb + 1024]);
      float go = bf2f(gates[r * 136 + 96 + hc]) + bf2f(xUb[xb + 1536]);
      if (badf(gi + gf + gg + go)) atomicOr(diag, 1);
      float cc = sigf(gf) * bf2f(cb[(size_t)s * 512 + col]) + sigf(gi) * tanh_f(gg);
      cb[(size_t)s * 512 + col] = f2bf(cc);
      hout[(size_t)s * 512 + col] = f2bf(sigf(go) * tanh_f(cc));
    } else {
      hout[(size_t)s * 512 + col] = hin[(size_t)s * 512 + col];
    }
  }
}

// ---------------- P GEMM: P[M=4096, N=1024](bf16) = [word_emb[wseq] f32 | h bf16] @ Wih^T(f32)
__global__ __launch_bounds__(256) void gemm_gather_nt_k(
    const float* __restrict__ wemb,
    const int* __restrict__ wseq,
    const unsigned short* __restrict__ hbuf,
    const float* __restrict__ B,              // [1024,1024] f32
    unsigned short* __restrict__ P)           // [4096,1024] bf16
{
  __shared__ __align__(16) unsigned short As[128 * 32];
  __shared__ __align__(16) unsigned short Bs[128 * 32];
  const int tid = threadIdx.x;
  const int m0 = blockIdx.y * 128;
  const int n0 = blockIdx.x * 128;
  const int wave = tid >> 6;
  const int lane = tid & 63;
  const int wm = (wave >> 1) * 64;
  const int wn = (wave & 1) * 64;
  float4v z = {0.f, 0.f, 0.f, 0.f};
  float4v acc[4][4];
#pragma unroll
  for (int i = 0; i < 4; ++i)
#pragma unroll
    for (int j = 0; j < 4; ++j) acc[i][j] = z;

  for (int k0 = 0; k0 < 1024; k0 += 32) {
    __syncthreads();
#pragma unroll
    for (int i = 0; i < 2; ++i) {
      int chunk = tid * 2 + i;
      int row = chunk >> 2;
      int k8 = (chunk & 3) * 8;
      int arow = m0 + row;
      int acol = k0 + k8;
      if (acol < 512) {
        *(int4*)(As + row * 32 + k8) = cvt8(wemb + (size_t)wseq[arow] * 512 + acol);
      } else {
        int4 av = *(const int4*)(hbuf + (size_t)arow * 512 + (acol - 512));
        *(int4*)(As + row * 32 + k8) = av;
      }
      *(int4*)(Bs + row * 32 + k8) = cvt8(B + (size_t)(n0 + row) * 1024 + k0 + k8);
    }
    __syncthreads();
    short8 af[4], bfr[4];
    const int kq = (lane >> 4) * 8;
#pragma unroll
    for (int i = 0; i < 4; ++i) {
      af[i]  = *(const short8*)(As + (wm + i * 16 + (lane & 15)) * 32 + kq);
      bfr[i] = *(const short8*)(Bs + (wn + i * 16 + (lane & 15)) * 32 + kq);
    }
#pragma unroll
    for (int i = 0; i < 4; ++i)
#pragma unroll
      for (int j = 0; j < 4; ++j)
        acc[i][j] = __builtin_amdgcn_mfma_f32_16x16x32_bf16(af[i], bfr[j], acc[i][j], 0, 0, 0);
  }
#pragma unroll
  for (int i = 0; i < 4; ++i)
#pragma unroll
    for (int j = 0; j < 4; ++j)
#pragma unroll
      for (int r = 0; r < 4; ++r) {
        int row = m0 + wm + i * 16 + (lane >> 4) * 4 + r;
        int col = n0 + wn + j * 16 + (lane & 15);
        P[(size_t)row * 1024 + col] = f2bf(acc[i][j][r]);
      }
}

// ---------------- scan v4: ONE block per direction; pair-per-unit, shuffle gate exchange.
// Thread pair (2u, 2u+1) owns hidden unit u: even computes gate rows (i:u, f:256+u),
// odd computes (g:512+u, o:768+u). Weights: 23 q4-chunks/row in VGPR (184 regs) +
// 9 chunks in LDS SoA (144 KB, unit-stride b128). h double-buffered (1 KB), c in VGPR,
// ONE barrier/step. amdgpu_waves_per_eu(2,2) pins the 256-VGPR tier.
__global__ __launch_bounds__(512)
__attribute__((amdgpu_waves_per_eu(2, 2)))
void scan4_k(
    const unsigned short* __restrict__ P_f,   // [4096,1024] bf16
    const unsigned short* __restrict__ P_b,
    const unsigned int* __restrict__ Wpk,     // [2][32][1024][4] u32 (f16x2)
    const float* __restrict__ biasbuf,        // [2][1024] f32
    unsigned short* __restrict__ out_f,       // [4096,256] bf16
    unsigned short* __restrict__ out_b,
    int* __restrict__ diag, int dirsel)
{
  const int dir = (dirsel < 0) ? (int)blockIdx.x : dirsel;
  const int tid = threadIdx.x;
  const int u   = tid >> 1;                 // hidden unit 0..255
  const int odd = tid & 1;
  const int rA  = u + odd * 512;            // even: gate i row; odd: gate g row
  const int rB  = rA + 256;                 // even: gate f row; odd: gate o row

  __shared__ __align__(16) uint4 ldsWa[9 * 512];        // 72 KB, chunks q4=23..31, row rA
  __shared__ __align__(16) uint4 ldsWb[9 * 512];        // 72 KB, row rB
  __shared__ __align__(16) unsigned short h16[2][256];  // f16 h state, double-buffered

  const uint4* wp = (const uint4*)Wpk + (size_t)dir * 32 * 1024;
  uint4 wA[23], wB[23];
#pragma unroll
  for (int q4 = 0; q4 < 23; ++q4) {
    wA[q4] = wp[q4 * 1024 + rA];
    wB[q4] = wp[q4 * 1024 + rB];
  }
#pragma unroll
  for (int q = 0; q < 9; ++q) {
    ldsWa[q * 512 + tid] = wp[(23 + q) * 1024 + rA];
    ldsWb[q * 512 + tid] = wp[(23 + q) * 1024 + rB];
  }
  const float bA = biasbuf[dir * 1024 + rA];
  const float bB = biasbuf[dir * 1024 + rB];
  const unsigned short* P = dir ? P_b : P_f;
  unsigned short* out = dir ? out_b : out_f;

  if (!odd) h16[0][u] = 0;
  float c_reg = 0.f;
  __syncthreads();

  // P prefetch for t=0
  int srow0 = dir ? 4095 : 0;
  float pA = bf2f(P[(size_t)srow0 * 1024 + rA]);
  float pB = bf2f(P[(size_t)srow0 * 1024 + rB]);

  for (int t = 0; t < 4096; ++t) {
    const int srow = dir ? (4095 - t) : t;
    // branchless prefetch of next-step P (wraps harmlessly at the end)
    const int nrow = dir ? ((4094 - t) & 4095) : ((t + 1) & 4095);
    float npA = bf2f(P[(size_t)nrow * 1024 + rA]);
    float npB = bf2f(P[(size_t)nrow * 1024 + rB]);

    float accA = 0.f, accB = 0.f;
    const uint4* h4 = (const uint4*)&h16[t & 1][0];   // 32 broadcast chunks of 8 f16
#pragma unroll
    for (int q4 = 0; q4 < 23; ++q4) {
      uint4 hv = h4[q4];
      accA = fdot2u(wA[q4].x, hv.x, accA);
      accA = fdot2u(wA[q4].y, hv.y, accA);
      accA = fdot2u(wA[q4].z, hv.z, accA);
      accA = fdot2u(wA[q4].w, hv.w, accA);
      accB = fdot2u(wB[q4].x, hv.x, accB);
      accB = fdot2u(wB[q4].y, hv.y, accB);
      accB = fdot2u(wB[q4].z, hv.z, accB);
      accB = fdot2u(wB[q4].w, hv.w, accB);
    }
#pragma unroll
    for (int q = 0; q < 9; ++q) {
      uint4 hv = h4[23 + q];
      uint4 wa = ldsWa[q * 512 + tid];
      uint4 wb = ldsWb[q * 512 + tid];
      accA = fdot2u(wa.x, hv.x, accA);
      accA = fdot2u(wa.y, hv.y, accA);
      accA = fdot2u(wa.z, hv.z, accA);
      accA = fdot2u(wa.w, hv.w, accA);
      accB = fdot2u(wb.x, hv.x, accB);
      accB = fdot2u(wb.y, hv.y, accB);
      accB = fdot2u(wb.z, hv.z, accB);
      accB = fdot2u(wb.w, hv.w, accB);
    }
    accA += bA + pA;
    accB += bB + pB;
    // pairwise gate exchange: even holds (i,f), odd holds (g,o)
    float a1 = __shfl_xor(accA, 1);
    float b1 = __shfl_xor(accB, 1);
    float gi = odd ? a1   : accA;
    float gf = odd ? b1   : accB;
    float gg = odd ? accA : a1;
    float go = odd ? accB : b1;
    if (badf(gi + gf + gg + go)) atomicOr(diag, 2);
    float cc = sigf(gf) * c_reg + sigf(gi) * tanh_f(gg);
    float hh = sigf(go) * tanh_f(cc);
    c_reg = cc;
    if (!odd) {
      h16[(t + 1) & 1][u] = f2h(hh);
      out[(size_t)srow * HHD + u] = f2bf(hh);
    }
    pA = npA; pB = npB;
    __syncthreads();            // new h buffer ready; old buffer fully consumed
  }
}

// ---------------- heads: logits + log_softmax -> f32 out
__global__ __launch_bounds__(128) void head_k(
    const unsigned short* __restrict__ out_f, const unsigned short* __restrict__ out_b,
    const float* __restrict__ Wpos, const float* __restrict__ bpos,
    const float* __restrict__ Wner, const float* __restrict__ bner,
    float* __restrict__ dout, int* __restrict__ diag)
{
  const int s = blockIdx.x, tid = threadIdx.x;
  __shared__ __align__(16) float xv[512];
#pragma unroll
  for (int i = 0; i < 4; ++i) {
    int k = tid * 4 + i;
    xv[k] = (k < 256) ? bf2f(out_f[(size_t)s * 256 + k])
                      : bf2f(out_b[(size_t)s * 256 + (k - 256)]);
  }
  __syncthreads();
  float logit = 0.f;
  const int j = tid;
  if (j < 96) {
    const float* wr = (j < 64) ? (Wpos + (size_t)j * 512)
                               : (Wner + (size_t)(j - 64) * 512);
    float b = (j < 64) ? bpos[j] : bner[j - 64];
    float acc = 0.f;
    for (int k = 0; k < 512; k += 4) {
      float4 wv = *(const float4*)(wr + k);
      acc += xv[k] * wv.x + xv[k + 1] * wv.y + xv[k + 2] * wv.z + xv[k + 3] * wv.w;
    }
    logit = acc + b;
    if (badf(logit)) { atomicOr(diag, 4); logit = 0.f; }
  }
  if (j < 64) {
    float m = logit;
    for (int o = 32; o >= 1; o >>= 1) m = fmaxf(m, __shfl_xor(m, o));
    float e = __expf(logit - m), sum = e;
    for (int o = 32; o >= 1; o >>= 1) sum += __shfl_xor(sum, o);
    float v = logit - m - logf(sum);
    if (!(v > -1e30f && v < 1e30f)) v = -111.f;
    dout[(size_t)s * 64 + j] = v;
  } else if (j < 96) {
    float m = logit;
    for (int o = 16; o >= 1; o >>= 1) m = fmaxf(m, __shfl_xor(m, o, 32));
    float e = __expf(logit - m), sum = e;
    for (int o = 16; o >= 1; o >>= 1) sum += __shfl_xor(sum, o, 32);
    float v = logit - m - logf(sum);
    if (!(v > -1e30f && v < 1e30f)) v = -111.f;
    dout[262144 + (size_t)s * 32 + (j - 64)] = v;
  }
}

// ---------------- diagnostics (silent when healthy)
__global__ void diag_k(const float* __restrict__ ce,
                       int* __restrict__ diag,
                       float* __restrict__ dout)
{
  int cnt = 0;
  for (int i = 0; i < 64; ++i) {
    float x = ce[i];
    if (x == x && fabsf(x) < 100.f) cnt++;
  }
  if (cnt < 48) diag[0] |= 8;
  int d = diag[0];
  if (d) dout[0] = 1000.f + 100.f * (float)d;
}

__global__ void wssmall_k(float* __restrict__ dout, int mb)
{
  dout[0] = 10000.f + (float)mb;
}

extern "C" void kernel_launch(void* const* d_in, const int* in_sizes, int n_in,
                              void* d_out, int out_size, void* d_ws, size_t ws_size,
                              hipStream_t stream) {
  const int*   word_seq  = (const int*)d_in[0];
  const int*   chars     = (const int*)d_in[1];
  const int*   char_lens = (const int*)d_in[2];
  const int*   feat_seq  = (const int*)d_in[3];
  const float* char_emb  = (const float*)d_in[4];
  const float* word_emb  = (const float*)d_in[5];
  const float* prefix_emb= (const float*)d_in[6];
  const float* Wih_c     = (const float*)d_in[7];
  const float* Whh_c     = (const float*)d_in[8];
  const float* bih_c     = (const float*)d_in[9];
  const float* bhh_c     = (const float*)d_in[10];
  const float* Wih_f     = (const float*)d_in[11];
  const float* Whh_f     = (const float*)d_in[12];
  const float* bih_f     = (const float*)d_in[13];
  const float* bhh_f     = (const float*)d_in[14];
  const float* Wih_b     = (const float*)d_in[15];
  const float* Whh_b     = (const float*)d_in[16];
  const float* bih_b     = (const float*)d_in[17];
  const float* bhh_b     = (const float*)d_in[18];
  const float* Wpos      = (const float*)d_in[19];
  const float* bpos      = (const float*)d_in[20];
  const float* Wner      = (const float*)d_in[21];
  const float* bner      = (const float*)d_in[22];
  float* dout = (float*)d_out;

  const size_t MB = 1048576;
  char* ws = (char*)d_ws;
  // small region
  int*            diag  = (int*)(ws + 512);           // 512 B
  float*          bias2 = (float*)(ws + 8192);        // 8 KB
  unsigned int*   Wpk   = (unsigned int*)(ws + 65536);// 1 MB, 16B-aligned
  // big region (phase-overlapped)
  unsigned short* hA    = (unsigned short*)(ws + 2 * MB);   // 4 MB [4096,512] bf16
  unsigned short* hB    = (unsigned short*)(ws + 6 * MB);   // 4 MB
  unsigned short* xUb   = (unsigned short*)(ws + 10 * MB);  // 2 MB [512,2048] bf16
  unsigned short* cb    = (unsigned short*)(ws + 12 * MB);  // 4 MB [4096,512] bf16

  const size_t NEED_A2 = 22 * MB;  // P_f 6..14, P_b 14..22 (both scans in parallel)
  const size_t NEED_B  = 16 * MB;  // sequential dir scans, shared P buffer
  unsigned short* P_f;
  unsigned short* P_b;
  unsigned short* out_f;
  unsigned short* out_b;
  int layoutA;
  if (ws_size >= NEED_A2) {
    layoutA = 1;
    P_f   = (unsigned short*)(ws + 6 * MB);    // over dead hB/xUb
    P_b   = (unsigned short*)(ws + 14 * MB);   // over dead cb + fresh
    out_f = (unsigned short*)(ws + 2 * MB);    // over dead hA
    out_b = (unsigned short*)(ws + 4 * MB);
  } else if (ws_size >= NEED_B) {
    layoutA = 0;
    P_f   = (unsigned short*)(ws + 6 * MB);
    P_b   = (unsigned short*)(ws + 6 * MB);
    out_f = (unsigned short*)(ws + 14 * MB);
    out_b = (unsigned short*)(ws + 2 * MB);
  } else {
    wssmall_k<<<1, 1, 0, stream>>>(dout, (int)(ws_size >> 20));
    return;
  }

  prep_xu_k<<<(512 * 2048) / 256, 256, 0, stream>>>(char_emb, Wih_c, bih_c, bhh_c, xUb);
  prep_h0c0_k<<<(4096 * 512) / 256, 256, 0, stream>>>(prefix_emb, feat_seq, hA, cb);
  prep_scanw2_k<<<(2 * 32 * 1024 * 4) / 256, 256, 0, stream>>>(
      Whh_f, Whh_b, bih_f, bhh_f, bih_b, bhh_b, Wpk, bias2, diag);

  unsigned short* hcur = hA;
  unsigned short* hnxt = hB;
  for (int t = 0; t < 16; ++t) {
    gemm_char_k<<<dim3(16, 32), 256, 0, stream>>>(
        hcur, Whh_c, xUb, chars, char_lens, t, hnxt, cb, diag);
    unsigned short* tmp = hcur; hcur = hnxt; hnxt = tmp;
  }
  // after 16 swaps, final char features are in hA (hcur == hA)

  if (layoutA) {
    gemm_gather_nt_k<<<dim3(8, 32), 256, 0, stream>>>(word_emb, word_seq, hcur, Wih_f, P_f);
    gemm_gather_nt_k<<<dim3(8, 32), 256, 0, stream>>>(word_emb, word_seq, hcur, Wih_b, P_b);
    scan4_k<<<2, 512, 0, stream>>>(P_f, P_b, Wpk, bias2, out_f, out_b, diag, -1);
  } else {
    gemm_gather_nt_k<<<dim3(8, 32), 256, 0, stream>>>(word_emb, word_seq, hcur, Wih_f, P_f);
    scan4_k<<<1, 512, 0, stream>>>(P_f, P_b, Wpk, bias2, out_f, out_b, diag, 0);
    gemm_gather_nt_k<<<dim3(8, 32), 256, 0, stream>>>(word_emb, word_seq, hcur, Wih_b, P_b);
    scan4_k<<<1, 512, 0, stream>>>(P_f, P_b, Wpk, bias2, out_f, out_b, diag, 1);
  }

  head_k<<<4096, 128, 0, stream>>>(out_f, out_b, Wpos, bpos, Wner, bner, dout, diag);

  diag_k<<<1, 1, 0, stream>>>(char_emb, diag, dout);
}

// Round 5
// 7980.833 us; speedup vs baseline: 1.1929x; 1.0563x over previous
//
#include <hip/hip_runtime.h>

#define SS 4096
#define LL 16
#define HD 512
#define ECD 128
#define HHD 256

typedef __attribute__((ext_vector_type(8))) short short8;
typedef __attribute__((ext_vector_type(4))) float float4v;
typedef _Float16 half2v __attribute__((ext_vector_type(2)));

__device__ __forceinline__ float bf2f(unsigned short u){
  union { unsigned int i; float f; } v; v.i = ((unsigned int)u) << 16; return v.f;
}
__device__ __forceinline__ unsigned short f2bf(float f){
  union { float f; unsigned int i; } v; v.f = f;
  unsigned int u = v.i;
  unsigned int r = (u + 0x7fffu + ((u >> 16) & 1u)) >> 16;
  return (unsigned short)r;
}
__device__ __forceinline__ unsigned short f2h(float x){
  _Float16 h = (_Float16)x;
  return __builtin_bit_cast(unsigned short, h);
}
__device__ __forceinline__ float sigf(float x){ return 1.f / (1.f + __expf(-x)); }
__device__ __forceinline__ float tanh_f(float x){
  float e = __expf(2.f * x);
  return 1.f - 2.f / (e + 1.f);
}
__device__ __forceinline__ float fdot2u(unsigned int a, unsigned int b, float c){
  half2v ha = __builtin_bit_cast(half2v, a);
  half2v hb = __builtin_bit_cast(half2v, b);
#if __has_builtin(__builtin_amdgcn_fdot2)
  return __builtin_amdgcn_fdot2(ha, hb, c, false);
#else
  return c + (float)ha[0]*(float)hb[0] + (float)ha[1]*(float)hb[1];
#endif
}
__device__ __forceinline__ unsigned int packf16(float lo, float hi){
  half2v h; h[0] = (_Float16)lo; h[1] = (_Float16)hi;
  return __builtin_bit_cast(unsigned int, h);
}
__device__ __forceinline__ bool badf(float x){ return !(fabsf(x) < 1e30f); }

// pack 8 f32 -> 8 bf16 (as int4) for LDS staging
__device__ __forceinline__ int4 cvt8(const float* __restrict__ s){
  union { unsigned short u[8]; int4 v; } pk;
#pragma unroll
  for (int i = 0; i < 8; ++i) pk.u[i] = f2bf(s[i]);
  return pk.v;
}

// ---------------- prep: xUb[c][n] = char_emb[c].Wih_c[n] + bih_c[n] + bhh_c[n]  (bf16 out)
__global__ void prep_xu_k(const float* __restrict__ char_emb,
                          const float* __restrict__ Wih_c,
                          const float* __restrict__ bih_c,
                          const float* __restrict__ bhh_c,
                          unsigned short* __restrict__ xUb)
{
  int idx = blockIdx.x * 256 + threadIdx.x;   // 512 * 2048
  int c = idx >> 11, n = idx & 2047;
  const float* ce = char_emb + (size_t)c * ECD;
  const float* wr = Wih_c + (size_t)n * ECD;
  float acc = bih_c[n] + bhh_c[n];
  for (int k = 0; k < ECD; k += 4) {
    float4 a = *(const float4*)(ce + k);
    float4 b = *(const float4*)(wr + k);
    acc += a.x*b.x + a.y*b.y + a.z*b.z + a.w*b.w;
  }
  xUb[idx] = f2bf(acc);
}

// ---------------- prep: h0 = prefix_emb[feat_seq] (bf16), c0 = 0 (bf16)
__global__ void prep_h0c0_k(const float* __restrict__ prefix_emb,
                            const int* __restrict__ feat_seq,
                            unsigned short* __restrict__ h0,
                            unsigned short* __restrict__ c0)
{
  int idx = blockIdx.x * 256 + threadIdx.x;  // 4096*512
  int s = idx >> 9, j = idx & 511;
  h0[idx] = f2bf(prefix_emb[(size_t)feat_seq[s] * HD + j]);
  c0[idx] = 0;
}

// ---------------- prep v3: pack Whh_{f,b} (f32) into [dir][q4 0..31][row 0..1023][j 0..3] u32 f16x2
// u32 index = (dir<<17) | (q4<<12) | (row<<2) | j ; covers k = 2*(q4*4+j), +1. Also zero hx.
__global__ void prep_scanw3_k(const float* __restrict__ Whh_f,
                              const float* __restrict__ Whh_b,
                              const float* __restrict__ bih_f,
                              const float* __restrict__ bhh_f,
                              const float* __restrict__ bih_b,
                              const float* __restrict__ bhh_b,
                              unsigned int* __restrict__ Wpk,
                              float* __restrict__ biasbuf,
                              unsigned int* __restrict__ hx,
                              int* __restrict__ diag)
{
  int idx = blockIdx.x * 256 + threadIdx.x;  // 2*32*1024*4 = 262144
  int j   = idx & 3;
  int row = (idx >> 2) & 1023;
  int q4  = (idx >> 12) & 31;
  int dir = (idx >> 17) & 1;
  int k = 2 * (q4 * 4 + j);
  const float* W = dir ? Whh_b : Whh_f;   // [1024,256] f32, rows gate-major i,f,g,o
  Wpk[idx] = packf16(W[(size_t)row * HHD + k], W[(size_t)row * HHD + k + 1]);
  if (idx < 2048) {
    int dr = idx >> 10, g = idx & 1023;
    biasbuf[idx] = dr ? (bih_b[g] + bhh_b[g]) : (bih_f[g] + bhh_f[g]);
  }
  // hx: 2 dirs x 2 slots x 256 tagged words; tag0|f16(0)==0 is the valid t=0 state
  if (idx < 1024) hx[idx] = 0u;
  if (idx == 0) diag[0] = 0;
}

// ---------------- fused char-step: gates = h_in @ Whh_c^T (MFMA), then LSTM cell epilogue
__global__ __launch_bounds__(256) void gemm_char_k(
    const unsigned short* __restrict__ hin,   // [4096,512] bf16
    const float* __restrict__ Whh,            // [2048,512] f32
    const unsigned short* __restrict__ xUb,   // [512,2048] bf16
    const int* __restrict__ chars,
    const int* __restrict__ lens,
    int t,
    unsigned short* __restrict__ hout,        // [4096,512] bf16
    unsigned short* __restrict__ cb,          // [4096,512] bf16 (in/out)
    int* __restrict__ diag)
{
  __shared__ __align__(16) unsigned short As[128 * 32];
  __shared__ __align__(16) unsigned short Bs[128 * 32];
  __shared__ __align__(16) unsigned short gates[128 * 136];
  const int tid = threadIdx.x;
  const int m0 = blockIdx.y * 128;
  const int n0h = blockIdx.x * 32;            // base h-column of this tile
  const int wave = tid >> 6;
  const int lane = tid & 63;
  const int wm = (wave >> 1) * 64;
  const int wn = (wave & 1) * 64;
  float4v z = {0.f, 0.f, 0.f, 0.f};
  float4v acc[4][4];
#pragma unroll
  for (int i = 0; i < 4; ++i)
#pragma unroll
    for (int j = 0; j < 4; ++j) acc[i][j] = z;

  for (int k0 = 0; k0 < 512; k0 += 32) {
    __syncthreads();
#pragma unroll
    for (int i = 0; i < 2; ++i) {
      int chunk = tid * 2 + i;           // 0..511
      int row = chunk >> 2;              // 0..127
      int k8 = (chunk & 3) * 8;
      int4 av = *(const int4*)(hin + (size_t)(m0 + row) * 512 + k0 + k8);
      *(int4*)(As + row * 32 + k8) = av;
      int br = (row >> 5) * 512 + n0h + (row & 31);
      *(int4*)(Bs + row * 32 + k8) = cvt8(Whh + (size_t)br * 512 + k0 + k8);
    }
    __syncthreads();
    short8 af[4], bfr[4];
    const int kq = (lane >> 4) * 8;
#pragma unroll
    for (int i = 0; i < 4; ++i) {
      af[i]  = *(const short8*)(As + (wm + i * 16 + (lane & 15)) * 32 + kq);
      bfr[i] = *(const short8*)(Bs + (wn + i * 16 + (lane & 15)) * 32 + kq);
    }
#pragma unroll
    for (int i = 0; i < 4; ++i)
#pragma unroll
      for (int j = 0; j < 4; ++j)
        acc[i][j] = __builtin_amdgcn_mfma_f32_16x16x32_bf16(af[i], bfr[j], acc[i][j], 0, 0, 0);
  }
  __syncthreads();
#pragma unroll
  for (int i = 0; i < 4; ++i)
#pragma unroll
    for (int j = 0; j < 4; ++j)
#pragma unroll
      for (int r = 0; r < 4; ++r) {
        int row = wm + i * 16 + (lane >> 4) * 4 + r;
        int col = wn + j * 16 + (lane & 15);
        gates[row * 136 + col] = f2bf(acc[i][j][r]);
      }
  __syncthreads();
#pragma unroll
  for (int e = 0; e < 16; ++e) {
    int idx = e * 256 + tid;
    int r = idx >> 5, hc = idx & 31;
    int s = m0 + r;
    int col = n0h + hc;
    if (t < lens[s]) {
      int cid = chars[s * LL + t];
      size_t xb = (size_t)cid * 2048 + col;
      float gi = bf2f(gates[r * 136 + hc])      + bf2f(xUb[xb]);
      float gf = bf2f(gates[r * 136 + 32 + hc]) + bf2f(xUb[xb + 512]);
      float gg = bf2f(gates[r * 136 + 64 + hc]) + bf2f(xUb[xb + 1024]);
      float go = bf2f(gates[r * 136 + 96 + hc]) + bf2f(xUb[xb + 1536]);
      if (badf(gi + gf + gg + go)) atomicOr(diag, 1);
      float cc = sigf(gf) * bf2f(cb[(size_t)s * 512 + col]) + sigf(gi) * tanh_f(gg);
      cb[(size_t)s * 512 + col] = f2bf(cc);
      hout[(size_t)s * 512 + col] = f2bf(sigf(go) * tanh_f(cc));
    } else {
      hout[(size_t)s * 512 + col] = hin[(size_t)s * 512 + col];
    }
  }
}

// ---------------- P GEMM: P[M=4096, N=1024](bf16) = [word_emb[wseq] f32 | h bf16] @ Wih^T(f32)
__global__ __launch_bounds__(256) void gemm_gather_nt_k(
    const float* __restrict__ wemb,
    const int* __restrict__ wseq,
    const unsigned short* __restrict__ hbuf,
    const float* __restrict__ B,              // [1024,1024] f32
    unsigned short* __restrict__ P)           // [4096,1024] bf16
{
  __shared__ __align__(16) unsigned short As[128 * 32];
  __shared__ __align__(16) unsigned short Bs[128 * 32];
  const int tid = threadIdx.x;
  const int m0 = blockIdx.y * 128;
  const int n0 = blockIdx.x * 128;
  const int wave = tid >> 6;
  const int lane = tid & 63;
  const int wm = (wave >> 1) * 64;
  const int wn = (wave & 1) * 64;
  float4v z = {0.f, 0.f, 0.f, 0.f};
  float4v acc[4][4];
#pragma unroll
  for (int i = 0; i < 4; ++i)
#pragma unroll
    for (int j = 0; j < 4; ++j) acc[i][j] = z;

  for (int k0 = 0; k0 < 1024; k0 += 32) {
    __syncthreads();
#pragma unroll
    for (int i = 0; i < 2; ++i) {
      int chunk = tid * 2 + i;
      int row = chunk >> 2;
      int k8 = (chunk & 3) * 8;
      int arow = m0 + row;
      int acol = k0 + k8;
      if (acol < 512) {
        *(int4*)(As + row * 32 + k8) = cvt8(wemb + (size_t)wseq[arow] * 512 + acol);
      } else {
        int4 av = *(const int4*)(hbuf + (size_t)arow * 512 + (acol - 512));
        *(int4*)(As + row * 32 + k8) = av;
      }
      *(int4*)(Bs + row * 32 + k8) = cvt8(B + (size_t)(n0 + row) * 1024 + k0 + k8);
    }
    __syncthreads();
    short8 af[4], bfr[4];
    const int kq = (lane >> 4) * 8;
#pragma unroll
    for (int i = 0; i < 4; ++i) {
      af[i]  = *(const short8*)(As + (wm + i * 16 + (lane & 15)) * 32 + kq);
      bfr[i] = *(const short8*)(Bs + (wn + i * 16 + (lane & 15)) * 32 + kq);
    }
#pragma unroll
    for (int i = 0; i < 4; ++i)
#pragma unroll
      for (int j = 0; j < 4; ++j)
        acc[i][j] = __builtin_amdgcn_mfma_f32_16x16x32_bf16(af[i], bfr[j], acc[i][j], 0, 0, 0);
  }
#pragma unroll
  for (int i = 0; i < 4; ++i)
#pragma unroll
    for (int j = 0; j < 4; ++j)
#pragma unroll
      for (int r = 0; r < 4; ++r) {
        int row = m0 + wm + i * 16 + (lane >> 4) * 4 + r;
        int col = n0 + wn + j * 16 + (lane & 15);
        P[(size_t)row * 1024 + col] = f2bf(acc[i][j][r]);
      }
}

// ---------------- scan v5: TWO blocks per direction. Block b owns units [b*128, b*128+128):
// all 4 gates of those units (512 gate rows, K=256). Weights per block = 256 KB:
// own-k half (k in [b*128,b*128+128)) in VGPR (16 uint4 = 64 regs/thread),
// remote-k half in LDS (128 KB, unit-stride b128). Per step: publish 128 tagged h via
// agent-scope atomics (round-0 proven scheme), poll remote 128. Poll issued before the
// own-half dot to hide L2 latency. 3 barriers/step.
__global__ __launch_bounds__(512) void scan5_k(
    const unsigned short* __restrict__ P_f,   // [4096,1024] bf16
    const unsigned short* __restrict__ P_b,
    const unsigned int* __restrict__ Wpk,     // [2][32][1024][4] u32 (f16x2)
    const float* __restrict__ biasbuf,        // [2][1024] f32
    unsigned short* __restrict__ out_f,       // [4096,256] bf16
    unsigned short* __restrict__ out_b,
    unsigned int* hx, int* __restrict__ diag, int dirsel)
{
  int dir, b;
  if (dirsel < 0) { dir = blockIdx.x >> 1; b = blockIdx.x & 1; }
  else            { dir = dirsel;          b = blockIdx.x; }
  const int tid  = threadIdx.x;
  const int gate = tid >> 7;                      // 0..3 (i,f,g,o)
  const int ul   = tid & 127;                     // local unit
  const int grow = gate * 256 + b * 128 + ul;     // global gate row
  const int rb   = 1 - b;

  __shared__ __align__(16) uint4 ldsW[16 * 512];        // 128 KB remote-k weights [q][tid]
  __shared__ __align__(16) float g_lds[512];
  __shared__ __align__(16) float c_lds[128];
  __shared__ __align__(16) unsigned short h_own[128];   // f16, own units
  __shared__ __align__(16) unsigned short h_rem[128];   // f16, remote units

  const uint4* wp = (const uint4*)Wpk + (size_t)dir * 32 * 1024;
  uint4 wv[16];
#pragma unroll
  for (int q = 0; q < 16; ++q) wv[q] = wp[(b * 16 + q) * 1024 + grow];
#pragma unroll
  for (int q = 0; q < 16; ++q) ldsW[q * 512 + tid] = wp[(rb * 16 + q) * 1024 + grow];

  const float bias = biasbuf[dir * 1024 + grow];
  const unsigned short* P = dir ? P_b : P_f;
  unsigned short* out = dir ? out_b : out_f;
  unsigned int* hxd = hx + dir * 512;

  if (tid < 128) { h_own[tid] = 0; h_rem[tid] = 0; c_lds[tid] = 0.f; }
  __syncthreads();

  int srow0 = dir ? 4095 : 0;
  float pv = bf2f(P[(size_t)srow0 * 1024 + grow]);

  for (int t = 0; t < 4096; ++t) {
    const int srow = dir ? (4095 - t) : t;
    const int nrow = dir ? ((4094 - t) & 4095) : ((t + 1) & 4095);
    float npv = bf2f(P[(size_t)nrow * 1024 + grow]);

    // issue first poll load early (latency hides under own-half dot)
    unsigned int pollv = 0;
    unsigned int* src = hxd + ((t & 1) << 8) + rb * 128 + ul;
    if (tid < 128) pollv = __hip_atomic_load(src, __ATOMIC_RELAXED, __HIP_MEMORY_SCOPE_AGENT);

    float acc = 0.f;
    const uint4* ho4 = (const uint4*)h_own;
#pragma unroll
    for (int q = 0; q < 16; ++q) {
      uint4 hv = ho4[q];
      acc = fdot2u(wv[q].x, hv.x, acc);
      acc = fdot2u(wv[q].y, hv.y, acc);
      acc = fdot2u(wv[q].z, hv.z, acc);
      acc = fdot2u(wv[q].w, hv.w, acc);
    }

    if (tid < 128) {
      while ((pollv >> 16) != (unsigned)t)
        pollv = __hip_atomic_load(src, __ATOMIC_RELAXED, __HIP_MEMORY_SCOPE_AGENT);
      h_rem[tid] = (unsigned short)(pollv & 0xffffu);
    }
    __syncthreads();            // h_rem ready

    const uint4* hr4 = (const uint4*)h_rem;
#pragma unroll
    for (int q = 0; q < 16; ++q) {
      uint4 hv = hr4[q];
      uint4 w = ldsW[q * 512 + tid];
      acc = fdot2u(w.x, hv.x, acc);
      acc = fdot2u(w.y, hv.y, acc);
      acc = fdot2u(w.z, hv.z, acc);
      acc = fdot2u(w.w, hv.w, acc);
    }
    g_lds[tid] = acc + bias + pv;
    __syncthreads();            // gates ready

    // cell: computed redundantly by all 4 gate-threads of unit ul (same value)
    float gi = g_lds[ul], gf = g_lds[128 + ul], gg = g_lds[256 + ul], go = g_lds[384 + ul];
    if (badf(gi + gf + gg + go) && tid < 128) atomicOr(diag, 2);
    float cc = sigf(gf) * c_lds[ul] + sigf(gi) * tanh_f(gg);
    float hh = sigf(go) * tanh_f(cc);
    if (tid < 128) {
      unsigned short hv16 = f2h(hh);
      // publish FIRST to minimize cross-CU latency
      __hip_atomic_store(hxd + (((t + 1) & 1) << 8) + b * 128 + tid,
                         ((unsigned)(t + 1) << 16) | (unsigned)hv16,
                         __ATOMIC_RELAXED, __HIP_MEMORY_SCOPE_AGENT);
      h_own[tid] = hv16;
      c_lds[tid] = cc;
      out[(size_t)srow * HHD + b * 128 + tid] = f2bf(hh);
    }
    pv = npv;
    __syncthreads();            // h_own/c ready; g_lds consumed
  }
}

// ---------------- heads: logits + log_softmax -> f32 out
__global__ __launch_bounds__(128) void head_k(
    const unsigned short* __restrict__ out_f, const unsigned short* __restrict__ out_b,
    const float* __restrict__ Wpos, const float* __restrict__ bpos,
    const float* __restrict__ Wner, const float* __restrict__ bner,
    float* __restrict__ dout, int* __restrict__ diag)
{
  const int s = blockIdx.x, tid = threadIdx.x;
  __shared__ __align__(16) float xv[512];
#pragma unroll
  for (int i = 0; i < 4; ++i) {
    int k = tid * 4 + i;
    xv[k] = (k < 256) ? bf2f(out_f[(size_t)s * 256 + k])
                      : bf2f(out_b[(size_t)s * 256 + (k - 256)]);
  }
  __syncthreads();
  float logit = 0.f;
  const int j = tid;
  if (j < 96) {
    const float* wr = (j < 64) ? (Wpos + (size_t)j * 512)
                               : (Wner + (size_t)(j - 64) * 512);
    float b = (j < 64) ? bpos[j] : bner[j - 64];
    float acc = 0.f;
    for (int k = 0; k < 512; k += 4) {
      float4 wv = *(const float4*)(wr + k);
      acc += xv[k] * wv.x + xv[k + 1] * wv.y + xv[k + 2] * wv.z + xv[k + 3] * wv.w;
    }
    logit = acc + b;
    if (badf(logit)) { atomicOr(diag, 4); logit = 0.f; }
  }
  if (j < 64) {
    float m = logit;
    for (int o = 32; o >= 1; o >>= 1) m = fmaxf(m, __shfl_xor(m, o));
    float e = __expf(logit - m), sum = e;
    for (int o = 32; o >= 1; o >>= 1) sum += __shfl_xor(sum, o);
    float v = logit - m - logf(sum);
    if (!(v > -1e30f && v < 1e30f)) v = -111.f;
    dout[(size_t)s * 64 + j] = v;
  } else if (j < 96) {
    float m = logit;
    for (int o = 16; o >= 1; o >>= 1) m = fmaxf(m, __shfl_xor(m, o, 32));
    float e = __expf(logit - m), sum = e;
    for (int o = 16; o >= 1; o >>= 1) sum += __shfl_xor(sum, o, 32);
    float v = logit - m - logf(sum);
    if (!(v > -1e30f && v < 1e30f)) v = -111.f;
    dout[262144 + (size_t)s * 32 + (j - 64)] = v;
  }
}

// ---------------- diagnostics (silent when healthy)
__global__ void diag_k(const float* __restrict__ ce,
                       int* __restrict__ diag,
                       float* __restrict__ dout)
{
  int cnt = 0;
  for (int i = 0; i < 64; ++i) {
    float x = ce[i];
    if (x == x && fabsf(x) < 100.f) cnt++;
  }
  if (cnt < 48) diag[0] |= 8;
  int d = diag[0];
  if (d) dout[0] = 1000.f + 100.f * (float)d;
}

__global__ void wssmall_k(float* __restrict__ dout, int mb)
{
  dout[0] = 10000.f + (float)mb;
}

extern "C" void kernel_launch(void* const* d_in, const int* in_sizes, int n_in,
                              void* d_out, int out_size, void* d_ws, size_t ws_size,
                              hipStream_t stream) {
  const int*   word_seq  = (const int*)d_in[0];
  const int*   chars     = (const int*)d_in[1];
  const int*   char_lens = (const int*)d_in[2];
  const int*   feat_seq  = (const int*)d_in[3];
  const float* char_emb  = (const float*)d_in[4];
  const float* word_emb  = (const float*)d_in[5];
  const float* prefix_emb= (const float*)d_in[6];
  const float* Wih_c     = (const float*)d_in[7];
  const float* Whh_c     = (const float*)d_in[8];
  const float* bih_c     = (const float*)d_in[9];
  const float* bhh_c     = (const float*)d_in[10];
  const float* Wih_f     = (const float*)d_in[11];
  const float* Whh_f     = (const float*)d_in[12];
  const float* bih_f     = (const float*)d_in[13];
  const float* bhh_f     = (const float*)d_in[14];
  const float* Wih_b     = (const float*)d_in[15];
  const float* Whh_b     = (const float*)d_in[16];
  const float* bih_b     = (const float*)d_in[17];
  const float* bhh_b     = (const float*)d_in[18];
  const float* Wpos      = (const float*)d_in[19];
  const float* bpos      = (const float*)d_in[20];
  const float* Wner      = (const float*)d_in[21];
  const float* bner      = (const float*)d_in[22];
  float* dout = (float*)d_out;

  const size_t MB = 1048576;
  char* ws = (char*)d_ws;
  // small region
  int*            diag  = (int*)(ws + 512);           // 512 B
  unsigned int*   hx    = (unsigned int*)(ws + 1024); // 4 KB (2 dirs x 2 slots x 256 u32)
  float*          bias2 = (float*)(ws + 8192);        // 8 KB
  unsigned int*   Wpk   = (unsigned int*)(ws + 65536);// 1 MB, 16B-aligned
  // big region (phase-overlapped)
  unsigned short* hA    = (unsigned short*)(ws + 2 * MB);   // 4 MB [4096,512] bf16
  unsigned short* hB    = (unsigned short*)(ws + 6 * MB);   // 4 MB
  unsigned short* xUb   = (unsigned short*)(ws + 10 * MB);  // 2 MB [512,2048] bf16
  unsigned short* cb    = (unsigned short*)(ws + 12 * MB);  // 4 MB [4096,512] bf16

  const size_t NEED_A2 = 22 * MB;  // P_f 6..14, P_b 14..22 (both scans in parallel)
  const size_t NEED_B  = 16 * MB;  // sequential dir scans, shared P buffer
  unsigned short* P_f;
  unsigned short* P_b;
  unsigned short* out_f;
  unsigned short* out_b;
  int layoutA;
  if (ws_size >= NEED_A2) {
    layoutA = 1;
    P_f   = (unsigned short*)(ws + 6 * MB);    // over dead hB/xUb
    P_b   = (unsigned short*)(ws + 14 * MB);   // over dead cb + fresh
    out_f = (unsigned short*)(ws + 2 * MB);    // over dead hA
    out_b = (unsigned short*)(ws + 4 * MB);
  } else if (ws_size >= NEED_B) {
    layoutA = 0;
    P_f   = (unsigned short*)(ws + 6 * MB);
    P_b   = (unsigned short*)(ws + 6 * MB);
    out_f = (unsigned short*)(ws + 14 * MB);
    out_b = (unsigned short*)(ws + 2 * MB);
  } else {
    wssmall_k<<<1, 1, 0, stream>>>(dout, (int)(ws_size >> 20));
    return;
  }

  prep_xu_k<<<(512 * 2048) / 256, 256, 0, stream>>>(char_emb, Wih_c, bih_c, bhh_c, xUb);
  prep_h0c0_k<<<(4096 * 512) / 256, 256, 0, stream>>>(prefix_emb, feat_seq, hA, cb);
  prep_scanw3_k<<<(2 * 32 * 1024 * 4) / 256, 256, 0, stream>>>(
      Whh_f, Whh_b, bih_f, bhh_f, bih_b, bhh_b, Wpk, bias2, hx, diag);

  unsigned short* hcur = hA;
  unsigned short* hnxt = hB;
  for (int t = 0; t < 16; ++t) {
    gemm_char_k<<<dim3(16, 32), 256, 0, stream>>>(
        hcur, Whh_c, xUb, chars, char_lens, t, hnxt, cb, diag);
    unsigned short* tmp = hcur; hcur = hnxt; hnxt = tmp;
  }
  // after 16 swaps, final char features are in hA (hcur == hA)

  if (layoutA) {
    gemm_gather_nt_k<<<dim3(8, 32), 256, 0, stream>>>(word_emb, word_seq, hcur, Wih_f, P_f);
    gemm_gather_nt_k<<<dim3(8, 32), 256, 0, stream>>>(word_emb, word_seq, hcur, Wih_b, P_b);
    scan5_k<<<4, 512, 0, stream>>>(P_f, P_b, Wpk, bias2, out_f, out_b, hx, diag, -1);
  } else {
    gemm_gather_nt_k<<<dim3(8, 32), 256, 0, stream>>>(word_emb, word_seq, hcur, Wih_f, P_f);
    scan5_k<<<2, 512, 0, stream>>>(P_f, P_b, Wpk, bias2, out_f, out_b, hx, diag, 0);
    gemm_gather_nt_k<<<dim3(8, 32), 256, 0, stream>>>(word_emb, word_seq, hcur, Wih_b, P_b);
    scan5_k<<<2, 512, 0, stream>>>(P_f, P_b, Wpk, bias2, out_f, out_b, hx, diag, 1);
  }

  head_k<<<4096, 128, 0, stream>>>(out_f, out_b, Wpos, bpos, Wner, bner, dout, diag);

  diag_k<<<1, 1, 0, stream>>>(char_emb, diag, dout);
}